// Round 1
// baseline (1234.958 us; speedup 1.0000x reference)
//
#include <hip/hip_runtime.h>
#include <cstddef>

static constexpr float ALPHA = 0.2f;
static constexpr int H = 64;

__device__ __forceinline__ float lrelu(float v) { return v >= 0.0f ? v : ALPHA * v; }

// out[rows,64] = act(in[rows,K] @ W[K,64] (+ bias))
template <int K, bool BIAS, bool ACT>
__global__ __launch_bounds__(256) void gemm_h64(
    const float* __restrict__ in, const float* __restrict__ W,
    const float* __restrict__ bias, float* __restrict__ out, int rows)
{
    __shared__ float Wl[K * H];
    for (int i = threadIdx.x; i < K * H; i += 256) Wl[i] = W[i];
    __syncthreads();

    const int col = threadIdx.x & 63;
    const int wv  = threadIdx.x >> 6;
    const int r0  = blockIdx.x * 16 + wv * 4;
    if (r0 >= rows) return;
    const int rm = rows - 1;
    const float* x0 = in + (size_t)min(r0 + 0, rm) * K;
    const float* x1 = in + (size_t)min(r0 + 1, rm) * K;
    const float* x2 = in + (size_t)min(r0 + 2, rm) * K;
    const float* x3 = in + (size_t)min(r0 + 3, rm) * K;

    float a0 = 0.f, a1 = 0.f, a2 = 0.f, a3 = 0.f;
    #pragma unroll 4
    for (int k = 0; k < K; k += 4) {
        float4 v0 = *(const float4*)(x0 + k);
        float4 v1 = *(const float4*)(x1 + k);
        float4 v2 = *(const float4*)(x2 + k);
        float4 v3 = *(const float4*)(x3 + k);
        float w0 = Wl[(k + 0) * H + col];
        float w1 = Wl[(k + 1) * H + col];
        float w2 = Wl[(k + 2) * H + col];
        float w3 = Wl[(k + 3) * H + col];
        a0 += v0.x * w0 + v0.y * w1 + v0.z * w2 + v0.w * w3;
        a1 += v1.x * w0 + v1.y * w1 + v1.z * w2 + v1.w * w3;
        a2 += v2.x * w0 + v2.y * w1 + v2.z * w2 + v2.w * w3;
        a3 += v3.x * w0 + v3.y * w1 + v3.z * w2 + v3.w * w3;
    }

    const float b = BIAS ? bias[col] : 0.0f;
    float r;
    r = a0 + b; if (ACT) r = lrelu(r); out[(size_t)(r0 + 0) * H + col] = r;
    if (r0 + 1 < rows) { r = a1 + b; if (ACT) r = lrelu(r); out[(size_t)(r0 + 1) * H + col] = r; }
    if (r0 + 2 < rows) { r = a2 + b; if (ACT) r = lrelu(r); out[(size_t)(r0 + 2) * H + col] = r; }
    if (r0 + 3 < rows) { r = a3 + b; if (ACT) r = lrelu(r); out[(size_t)(r0 + 3) * H + col] = r; }
}

__global__ __launch_bounds__(256) void fillf(float* __restrict__ p, float v, int n)
{
    int i = blockIdx.x * 256 + threadIdx.x;
    if (i < n) p[i] = v;
}

__global__ __launch_bounds__(256) void degadd(const int* __restrict__ dst, float* __restrict__ deg, int nE)
{
    int i = blockIdx.x * 256 + threadIdx.x;
    if (i < nE) atomicAdd(&deg[dst[i]], 1.0f);
}

__global__ __launch_bounds__(256) void findis(float* __restrict__ deg, int n)
{
    int i = blockIdx.x * 256 + threadIdx.x;
    if (i < n) {
        float d = deg[i];
        deg[i] = d > 0.0f ? rsqrtf(fmaxf(d, 1e-12f)) : 0.0f;
    }
}

// out[i,f] = h[i,f] * dis[i]^2  (self-loop term + zero-init of scatter target)
__global__ __launch_bounds__(256) void selfinit(const float* __restrict__ h, const float* __restrict__ dis,
                                                float* __restrict__ out, int n)
{
    int i = blockIdx.x * 256 + threadIdx.x;
    if (i < n * H) {
        float ds = dis[i >> 6];
        out[i] = h[i] * ds * ds;
    }
}

// out[dst] += h[src] * dis[src]*dis[dst], one wave per edge, lane = feature
__global__ __launch_bounds__(256) void scatter(const float* __restrict__ h, const int* __restrict__ src,
                                               const int* __restrict__ dst, const float* __restrict__ dis,
                                               float* __restrict__ out, int nE)
{
    int e = blockIdx.x * 4 + (threadIdx.x >> 6);
    if (e >= nE) return;
    int lane = threadIdx.x & 63;
    int s = src[e], d = dst[e];
    float nrm = dis[s] * dis[d];
    atomicAdd(&out[(size_t)d * H + lane], h[(size_t)s * H + lane] * nrm);
}

__global__ __launch_bounds__(256) void biasact(float* __restrict__ p, const float* __restrict__ bias, int n)
{
    int i = blockIdx.x * 256 + threadIdx.x;
    if (i < n * H) p[i] = lrelu(p[i] + bias[i & 63]);
}

__global__ __launch_bounds__(256) void copyf(const float* __restrict__ a, float* __restrict__ b, int n)
{
    int i = blockIdx.x * 256 + threadIdx.x;
    if (i < n) b[i] = a[i];
}

// logits = z @ Wc + bc  (C=2), then log_softmax; one wave per row
__global__ __launch_bounds__(256) void classifier(const float* __restrict__ z, const float* __restrict__ Wc,
                                                  const float* __restrict__ bc, float* __restrict__ out, int n)
{
    int row = blockIdx.x * 4 + (threadIdx.x >> 6);
    if (row >= n) return;
    int lane = threadIdx.x & 63;
    float v = z[(size_t)row * H + lane];
    float p0 = v * Wc[lane * 2 + 0];
    float p1 = v * Wc[lane * 2 + 1];
    #pragma unroll
    for (int off = 32; off; off >>= 1) {
        p0 += __shfl_xor(p0, off);
        p1 += __shfl_xor(p1, off);
    }
    if (lane == 0) {
        float l0 = p0 + bc[0], l1 = p1 + bc[1];
        float m = fmaxf(l0, l1);
        float lse = m + logf(expf(l0 - m) + expf(l1 - m));
        out[(size_t)row * 2 + 0] = l0 - lse;
        out[(size_t)row * 2 + 1] = l1 - lse;
    }
}

extern "C" void kernel_launch(void* const* d_in, const int* in_sizes, int n_in,
                              void* d_out, int out_size, void* d_ws, size_t ws_size,
                              hipStream_t stream)
{
    const float* x      = (const float*)d_in[0];
    const int*   ei     = (const int*)d_in[1];
    const float* mx     = (const float*)d_in[2];
    const int*   mei    = (const int*)d_in[3];
    const float* W_lin  = (const float*)d_in[4];
    const float* b_lin  = (const float*)d_in[5];
    const float* W_mlin = (const float*)d_in[6];
    const float* b_mlin = (const float*)d_in[7];
    const float* W0     = (const float*)d_in[8];
    const float* b0     = (const float*)d_in[9];
    const float* W1     = (const float*)d_in[10];
    const float* b1     = (const float*)d_in[11];
    const float* Wm     = (const float*)d_in[12];
    const float* bm     = (const float*)d_in[13];
    const float* Wc     = (const float*)d_in[14];
    const float* bc     = (const float*)d_in[15];

    const int F  = 128;
    const int N  = in_sizes[0] / F;
    const int E  = in_sizes[1] / 2;
    const int M  = in_sizes[2] / F;
    const int Em = in_sizes[3] / 2;
    const int NM = N + M;
    const int* src  = ei;
    const int* dstp = ei + E;
    const int* msrc = mei;
    const int* mdst = mei + Em;

    float* buf0 = (float*)d_ws;                 // [NM, H]
    float* buf1 = buf0 + (size_t)NM * H;        // [NM, H]
    float* mh   = buf1 + (size_t)NM * H;        // [M, H]
    float* dis  = mh + (size_t)M * H;           // [NM]

    const int nh  = N * H;
    const int nmh = NM * H;

    // input projections
    gemm_h64<128, true, true><<<(N + 15) / 16, 256, 0, stream>>>(x, W_lin, b_lin, buf0, N);
    gemm_h64<128, true, true><<<(M + 15) / 16, 256, 0, stream>>>(mx, W_mlin, b_mlin, mh, M);

    // data-graph normalization: deg = 1 (self loop) + indegree; dis = rsqrt(deg)
    fillf<<<(N + 255) / 256, 256, 0, stream>>>(dis, 1.0f, N);
    degadd<<<(E + 255) / 256, 256, 0, stream>>>(dstp, dis, E);
    findis<<<(N + 255) / 256, 256, 0, stream>>>(dis, N);

    // GCN layer 0
    gemm_h64<64, false, false><<<(N + 15) / 16, 256, 0, stream>>>(buf0, W0, nullptr, buf1, N);
    selfinit<<<(nh + 255) / 256, 256, 0, stream>>>(buf1, dis, buf0, N);
    scatter<<<(E + 3) / 4, 256, 0, stream>>>(buf1, src, dstp, dis, buf0, E);
    biasact<<<(nh + 255) / 256, 256, 0, stream>>>(buf0, b0, N);

    // GCN layer 1
    gemm_h64<64, false, false><<<(N + 15) / 16, 256, 0, stream>>>(buf0, W1, nullptr, buf1, N);
    selfinit<<<(nh + 255) / 256, 256, 0, stream>>>(buf1, dis, buf0, N);
    scatter<<<(E + 3) / 4, 256, 0, stream>>>(buf1, src, dstp, dis, buf0, E);
    biasact<<<(nh + 255) / 256, 256, 0, stream>>>(buf0, b1, N);

    // meta fusion: z = concat(h, mh); GCN with explicit loops in edge list
    copyf<<<(M * H + 255) / 256, 256, 0, stream>>>(mh, buf0 + (size_t)N * H, M * H);
    fillf<<<(NM + 255) / 256, 256, 0, stream>>>(dis, 0.0f, NM);
    degadd<<<(Em + 255) / 256, 256, 0, stream>>>(mdst, dis, Em);
    findis<<<(NM + 255) / 256, 256, 0, stream>>>(dis, NM);

    gemm_h64<64, false, false><<<(NM + 15) / 16, 256, 0, stream>>>(buf0, Wm, nullptr, buf1, NM);
    fillf<<<(nmh + 255) / 256, 256, 0, stream>>>(buf0, 0.0f, nmh);
    scatter<<<(Em + 3) / 4, 256, 0, stream>>>(buf1, msrc, mdst, dis, buf0, Em);
    biasact<<<(nmh + 255) / 256, 256, 0, stream>>>(buf0, bm, NM);

    // classifier + log_softmax
    classifier<<<(NM + 3) / 4, 256, 0, stream>>>(buf0, Wc, bc, (float*)d_out, NM);
}

// Round 2
// 806.703 us; speedup vs baseline: 1.5309x; 1.5309x over previous
//
#include <hip/hip_runtime.h>
#include <cstddef>

static constexpr float ALPHA = 0.2f;
static constexpr int H = 64;

__device__ __forceinline__ float lrelu(float v) { return v >= 0.0f ? v : ALPHA * v; }

// out[rows,64] = act(in[rows,K] @ W[K,64] (+ bias))
template <int K, bool BIAS, bool ACT>
__global__ __launch_bounds__(256) void gemm_h64(
    const float* __restrict__ in, const float* __restrict__ W,
    const float* __restrict__ bias, float* __restrict__ out, int rows)
{
    __shared__ float Wl[K * H];
    for (int i = threadIdx.x; i < K * H; i += 256) Wl[i] = W[i];
    __syncthreads();

    const int col = threadIdx.x & 63;
    const int wv  = threadIdx.x >> 6;
    const int r0  = blockIdx.x * 16 + wv * 4;
    if (r0 >= rows) return;
    const int rm = rows - 1;
    const float* x0 = in + (size_t)min(r0 + 0, rm) * K;
    const float* x1 = in + (size_t)min(r0 + 1, rm) * K;
    const float* x2 = in + (size_t)min(r0 + 2, rm) * K;
    const float* x3 = in + (size_t)min(r0 + 3, rm) * K;

    float a0 = 0.f, a1 = 0.f, a2 = 0.f, a3 = 0.f;
    #pragma unroll 4
    for (int k = 0; k < K; k += 4) {
        float4 v0 = *(const float4*)(x0 + k);
        float4 v1 = *(const float4*)(x1 + k);
        float4 v2 = *(const float4*)(x2 + k);
        float4 v3 = *(const float4*)(x3 + k);
        float w0 = Wl[(k + 0) * H + col];
        float w1 = Wl[(k + 1) * H + col];
        float w2 = Wl[(k + 2) * H + col];
        float w3 = Wl[(k + 3) * H + col];
        a0 += v0.x * w0 + v0.y * w1 + v0.z * w2 + v0.w * w3;
        a1 += v1.x * w0 + v1.y * w1 + v1.z * w2 + v1.w * w3;
        a2 += v2.x * w0 + v2.y * w1 + v2.z * w2 + v2.w * w3;
        a3 += v3.x * w0 + v3.y * w1 + v3.z * w2 + v3.w * w3;
    }

    const float b = BIAS ? bias[col] : 0.0f;
    float r;
    r = a0 + b; if (ACT) r = lrelu(r); out[(size_t)(r0 + 0) * H + col] = r;
    if (r0 + 1 < rows) { r = a1 + b; if (ACT) r = lrelu(r); out[(size_t)(r0 + 1) * H + col] = r; }
    if (r0 + 2 < rows) { r = a2 + b; if (ACT) r = lrelu(r); out[(size_t)(r0 + 2) * H + col] = r; }
    if (r0 + 3 < rows) { r = a3 + b; if (ACT) r = lrelu(r); out[(size_t)(r0 + 3) * H + col] = r; }
}

// ---------------- CSR build ----------------

__global__ __launch_bounds__(256) void zero_i(int* __restrict__ p, int n)
{
    int i = blockIdx.x * 256 + threadIdx.x;
    if (i < n) p[i] = 0;
}

__global__ __launch_bounds__(256) void count_edges(const int* __restrict__ dst, int* __restrict__ cnt, int nE)
{
    int i = blockIdx.x * 256 + threadIdx.x;
    if (i < nE) atomicAdd(&cnt[dst[i]], 1);
}

// per-block exclusive scan of 1024 elements; bsum[b] = block total
__global__ __launch_bounds__(256) void scan1(const int* __restrict__ cnt, int* __restrict__ rs,
                                             int* __restrict__ bsum, int n)
{
    __shared__ int lds[256];
    int t = threadIdx.x;
    int base = blockIdx.x * 1024 + t * 4;
    int v0 = 0, v1 = 0, v2 = 0, v3 = 0;
    if (base + 0 < n) v0 = cnt[base + 0];
    if (base + 1 < n) v1 = cnt[base + 1];
    if (base + 2 < n) v2 = cnt[base + 2];
    if (base + 3 < n) v3 = cnt[base + 3];
    int s = v0 + v1 + v2 + v3;
    lds[t] = s;
    __syncthreads();
    for (int off = 1; off < 256; off <<= 1) {
        int y = (t >= off) ? lds[t - off] : 0;
        __syncthreads();
        lds[t] += y;
        __syncthreads();
    }
    int excl = lds[t] - s;
    if (base + 0 < n) rs[base + 0] = excl;
    if (base + 1 < n) rs[base + 1] = excl + v0;
    if (base + 2 < n) rs[base + 2] = excl + v0 + v1;
    if (base + 3 < n) rs[base + 3] = excl + v0 + v1 + v2;
    if (t == 255) bsum[blockIdx.x] = lds[255];
}

// exclusive scan of block sums (nb <= 256)
__global__ __launch_bounds__(256) void scan2(int* __restrict__ bsum, int nb)
{
    __shared__ int lds[256];
    int t = threadIdx.x;
    int v = (t < nb) ? bsum[t] : 0;
    lds[t] = v;
    __syncthreads();
    for (int off = 1; off < 256; off <<= 1) {
        int y = (t >= off) ? lds[t - off] : 0;
        __syncthreads();
        lds[t] += y;
        __syncthreads();
    }
    if (t < nb) bsum[t] = lds[t] - v;
}

__global__ __launch_bounds__(256) void scan3(int* __restrict__ rs, int* __restrict__ cur,
                                             const int* __restrict__ bsum, int n)
{
    int i = blockIdx.x * 256 + threadIdx.x;
    if (i < n) {
        int r = rs[i] + bsum[i >> 10];
        rs[i] = r;
        cur[i] = r;
    }
}

__global__ __launch_bounds__(256) void fill_edges(const int* __restrict__ src, const int* __restrict__ dst,
                                                  int* __restrict__ cur, int* __restrict__ esrc, int nE)
{
    int e = blockIdx.x * 256 + threadIdx.x;
    if (e < nE) {
        int pos = atomicAdd(&cur[dst[e]], 1);
        esrc[pos] = src[e];
    }
}

__global__ __launch_bounds__(256) void mkdis(const int* __restrict__ cnt, float* __restrict__ dis,
                                             int n, int selfadd)
{
    int i = blockIdx.x * 256 + threadIdx.x;
    if (i < n) {
        int d = cnt[i] + selfadd;
        dis[i] = d > 0 ? rsqrtf((float)d) : 0.0f;
    }
}

// out[d] = lrelu( dis[d] * sum_e h[src_e]*dis[src_e]  (+ h[d]*dis[d]^2 if SELF) + bias )
template <bool SELF>
__global__ __launch_bounds__(256) void gather(const float* __restrict__ h, const int* __restrict__ esrc,
                                              const int* __restrict__ rs, const int* __restrict__ cnt,
                                              const float* __restrict__ dis, const float* __restrict__ bias,
                                              float* __restrict__ out, int n)
{
    int d = blockIdx.x * 4 + (threadIdx.x >> 6);
    if (d >= n) return;
    int lane = threadIdx.x & 63;
    int beg = rs[d];
    int c = cnt[d];
    float dd = dis[d];
    float a0 = 0.f, a1 = 0.f;
    int i = 0;
    for (; i + 2 <= c; i += 2) {
        int s0 = esrc[beg + i], s1 = esrc[beg + i + 1];
        float w0 = dis[s0], w1 = dis[s1];
        a0 += h[(size_t)s0 * H + lane] * w0;
        a1 += h[(size_t)s1 * H + lane] * w1;
    }
    if (i < c) {
        int s = esrc[beg + i];
        a0 += h[(size_t)s * H + lane] * dis[s];
    }
    float r = (a0 + a1) * dd;
    if (SELF) r += h[(size_t)d * H + lane] * dd * dd;
    out[(size_t)d * H + lane] = lrelu(r + bias[lane]);
}

// ---------------- fallback-path kernels (atomic scatter, R1) ----------------

__global__ __launch_bounds__(256) void fillf(float* __restrict__ p, float v, int n)
{
    int i = blockIdx.x * 256 + threadIdx.x;
    if (i < n) p[i] = v;
}

__global__ __launch_bounds__(256) void degadd(const int* __restrict__ dst, float* __restrict__ deg, int nE)
{
    int i = blockIdx.x * 256 + threadIdx.x;
    if (i < nE) atomicAdd(&deg[dst[i]], 1.0f);
}

__global__ __launch_bounds__(256) void findis(float* __restrict__ deg, int n)
{
    int i = blockIdx.x * 256 + threadIdx.x;
    if (i < n) {
        float d = deg[i];
        deg[i] = d > 0.0f ? rsqrtf(fmaxf(d, 1e-12f)) : 0.0f;
    }
}

__global__ __launch_bounds__(256) void selfinit(const float* __restrict__ h, const float* __restrict__ dis,
                                                float* __restrict__ out, int n)
{
    int i = blockIdx.x * 256 + threadIdx.x;
    if (i < n * H) {
        float ds = dis[i >> 6];
        out[i] = h[i] * ds * ds;
    }
}

__global__ __launch_bounds__(256) void scatter(const float* __restrict__ h, const int* __restrict__ src,
                                               const int* __restrict__ dst, const float* __restrict__ dis,
                                               float* __restrict__ out, int nE)
{
    int e = blockIdx.x * 4 + (threadIdx.x >> 6);
    if (e >= nE) return;
    int lane = threadIdx.x & 63;
    int s = src[e], d = dst[e];
    float nrm = dis[s] * dis[d];
    atomicAdd(&out[(size_t)d * H + lane], h[(size_t)s * H + lane] * nrm);
}

__global__ __launch_bounds__(256) void biasact(float* __restrict__ p, const float* __restrict__ bias, int n)
{
    int i = blockIdx.x * 256 + threadIdx.x;
    if (i < n * H) p[i] = lrelu(p[i] + bias[i & 63]);
}

// logits = z @ Wc + bc  (C=2), then log_softmax; one wave per row
__global__ __launch_bounds__(256) void classifier(const float* __restrict__ z, const float* __restrict__ Wc,
                                                  const float* __restrict__ bc, float* __restrict__ out, int n)
{
    int row = blockIdx.x * 4 + (threadIdx.x >> 6);
    if (row >= n) return;
    int lane = threadIdx.x & 63;
    float v = z[(size_t)row * H + lane];
    float p0 = v * Wc[lane * 2 + 0];
    float p1 = v * Wc[lane * 2 + 1];
    #pragma unroll
    for (int off = 32; off; off >>= 1) {
        p0 += __shfl_xor(p0, off);
        p1 += __shfl_xor(p1, off);
    }
    if (lane == 0) {
        float l0 = p0 + bc[0], l1 = p1 + bc[1];
        float m = fmaxf(l0, l1);
        float lse = m + logf(expf(l0 - m) + expf(l1 - m));
        out[(size_t)row * 2 + 0] = l0 - lse;
        out[(size_t)row * 2 + 1] = l1 - lse;
    }
}

extern "C" void kernel_launch(void* const* d_in, const int* in_sizes, int n_in,
                              void* d_out, int out_size, void* d_ws, size_t ws_size,
                              hipStream_t stream)
{
    const float* x      = (const float*)d_in[0];
    const int*   ei     = (const int*)d_in[1];
    const float* mx     = (const float*)d_in[2];
    const int*   mei    = (const int*)d_in[3];
    const float* W_lin  = (const float*)d_in[4];
    const float* b_lin  = (const float*)d_in[5];
    const float* W_mlin = (const float*)d_in[6];
    const float* b_mlin = (const float*)d_in[7];
    const float* W0     = (const float*)d_in[8];
    const float* b0     = (const float*)d_in[9];
    const float* W1     = (const float*)d_in[10];
    const float* b1     = (const float*)d_in[11];
    const float* Wm     = (const float*)d_in[12];
    const float* bm     = (const float*)d_in[13];
    const float* Wc     = (const float*)d_in[14];
    const float* bc     = (const float*)d_in[15];

    const int F  = 128;
    const int N  = in_sizes[0] / F;
    const int E  = in_sizes[1] / 2;
    const int M  = in_sizes[2] / F;
    const int Em = in_sizes[3] / 2;
    const int NM = N + M;
    const int* src  = ei;
    const int* dstp = ei + E;
    const int* msrc = mei;
    const int* mdst = mei + Em;

    const int Emax = E > Em ? E : Em;
    const size_t need = sizeof(float) * (2 * (size_t)NM * H + NM) +
                        sizeof(int) * (3 * (size_t)NM + (size_t)Emax + 512);

    float* buf0 = (float*)d_ws;                 // [NM, H]
    float* buf1 = buf0 + (size_t)NM * H;        // [NM, H]
    float* dis  = buf1 + (size_t)NM * H;        // [NM]
    int*   cnt  = (int*)(dis + NM);             // [NM]
    int*   rs   = cnt + NM;                     // [NM]
    int*   cur  = rs + NM;                      // [NM]
    int*   esrc = cur + NM;                     // [Emax]
    int*   bsum = esrc + Emax;                  // [<=256]

    const int nmh = NM * H;
    float* mdst_proj = buf0 + (size_t)N * H;    // meta rows live directly at buf0[N..NM)

    if (ws_size >= need) {
        // ---------- CSR gather path ----------
        // input projections (meta proj written straight into concat slot of buf0)
        gemm_h64<128, true, true><<<(N + 15) / 16, 256, 0, stream>>>(x, W_lin, b_lin, buf0, N);
        gemm_h64<128, true, true><<<(M + 15) / 16, 256, 0, stream>>>(mx, W_mlin, b_mlin, mdst_proj, M);

        // data-graph CSR (reused by both layers)
        const int nb1 = (N + 1023) / 1024;
        zero_i<<<(N + 255) / 256, 256, 0, stream>>>(cnt, N);
        count_edges<<<(E + 255) / 256, 256, 0, stream>>>(dstp, cnt, E);
        scan1<<<nb1, 256, 0, stream>>>(cnt, rs, bsum, N);
        scan2<<<1, 256, 0, stream>>>(bsum, nb1);
        scan3<<<(N + 255) / 256, 256, 0, stream>>>(rs, cur, bsum, N);
        fill_edges<<<(E + 255) / 256, 256, 0, stream>>>(src, dstp, cur, esrc, E);
        mkdis<<<(N + 255) / 256, 256, 0, stream>>>(cnt, dis, N, 1);

        // GCN layer 0
        gemm_h64<64, false, false><<<(N + 15) / 16, 256, 0, stream>>>(buf0, W0, nullptr, buf1, N);
        gather<true><<<(N + 3) / 4, 256, 0, stream>>>(buf1, esrc, rs, cnt, dis, b0, buf0, N);

        // GCN layer 1
        gemm_h64<64, false, false><<<(N + 15) / 16, 256, 0, stream>>>(buf0, W1, nullptr, buf1, N);
        gather<true><<<(N + 3) / 4, 256, 0, stream>>>(buf1, esrc, rs, cnt, dis, b1, buf0, N);

        // meta fusion over z = buf0[0..NM)
        gemm_h64<64, false, false><<<(NM + 15) / 16, 256, 0, stream>>>(buf0, Wm, nullptr, buf1, NM);

        const int nb2 = (NM + 1023) / 1024;
        zero_i<<<(NM + 255) / 256, 256, 0, stream>>>(cnt, NM);
        count_edges<<<(Em + 255) / 256, 256, 0, stream>>>(mdst, cnt, Em);
        scan1<<<nb2, 256, 0, stream>>>(cnt, rs, bsum, NM);
        scan2<<<1, 256, 0, stream>>>(bsum, nb2);
        scan3<<<(NM + 255) / 256, 256, 0, stream>>>(rs, cur, bsum, NM);
        fill_edges<<<(Em + 255) / 256, 256, 0, stream>>>(msrc, mdst, cur, esrc, Em);
        mkdis<<<(NM + 255) / 256, 256, 0, stream>>>(cnt, dis, NM, 0);

        gather<false><<<(NM + 3) / 4, 256, 0, stream>>>(buf1, esrc, rs, cnt, dis, bm, buf0, NM);

        classifier<<<(NM + 3) / 4, 256, 0, stream>>>(buf0, Wc, bc, (float*)d_out, NM);
    } else {
        // ---------- fallback: R1 atomic-scatter path ----------
        const int nh = N * H;
        gemm_h64<128, true, true><<<(N + 15) / 16, 256, 0, stream>>>(x, W_lin, b_lin, buf0, N);
        gemm_h64<128, true, true><<<(M + 15) / 16, 256, 0, stream>>>(mx, W_mlin, b_mlin, mdst_proj, M);

        fillf<<<(N + 255) / 256, 256, 0, stream>>>(dis, 1.0f, N);
        degadd<<<(E + 255) / 256, 256, 0, stream>>>(dstp, dis, E);
        findis<<<(N + 255) / 256, 256, 0, stream>>>(dis, N);

        gemm_h64<64, false, false><<<(N + 15) / 16, 256, 0, stream>>>(buf0, W0, nullptr, buf1, N);
        selfinit<<<(nh + 255) / 256, 256, 0, stream>>>(buf1, dis, buf0, N);
        scatter<<<(E + 3) / 4, 256, 0, stream>>>(buf1, src, dstp, dis, buf0, E);
        biasact<<<(nh + 255) / 256, 256, 0, stream>>>(buf0, b0, N);

        gemm_h64<64, false, false><<<(N + 15) / 16, 256, 0, stream>>>(buf0, W1, nullptr, buf1, N);
        selfinit<<<(nh + 255) / 256, 256, 0, stream>>>(buf1, dis, buf0, N);
        scatter<<<(E + 3) / 4, 256, 0, stream>>>(buf1, src, dstp, dis, buf0, E);
        biasact<<<(nh + 255) / 256, 256, 0, stream>>>(buf0, b1, N);

        fillf<<<(NM + 255) / 256, 256, 0, stream>>>(dis, 0.0f, NM);
        degadd<<<(Em + 255) / 256, 256, 0, stream>>>(mdst, dis, Em);
        findis<<<(NM + 255) / 256, 256, 0, stream>>>(dis, NM);

        gemm_h64<64, false, false><<<(NM + 15) / 16, 256, 0, stream>>>(buf0, Wm, nullptr, buf1, NM);
        fillf<<<(nmh + 255) / 256, 256, 0, stream>>>(buf0, 0.0f, nmh);
        scatter<<<(Em + 3) / 4, 256, 0, stream>>>(buf1, msrc, mdst, dis, buf0, Em);
        biasact<<<(nmh + 255) / 256, 256, 0, stream>>>(buf0, bm, NM);

        classifier<<<(NM + 3) / 4, 256, 0, stream>>>(buf0, Wc, bc, (float*)d_out, NM);
    }
}

// Round 3
// 562.538 us; speedup vs baseline: 2.1953x; 1.4340x over previous
//
#include <hip/hip_runtime.h>
#include <cstddef>

static constexpr float ALPHA = 0.2f;
static constexpr int H = 64;

typedef __attribute__((ext_vector_type(8))) short short8;
typedef __attribute__((ext_vector_type(4))) float floatx4;

__device__ __forceinline__ float lrelu(float v) { return v >= 0.0f ? v : ALPHA * v; }

__device__ __forceinline__ float b2f(unsigned short u)
{
    union { unsigned int i; float f; } x;
    x.i = ((unsigned int)u) << 16;
    return x.f;
}

__device__ __forceinline__ unsigned short f2b(float f)
{
    union { float f; unsigned int i; } x;
    x.f = f;
    unsigned int r = x.i + 0x7fffu + ((x.i >> 16) & 1u);  // RNE
    return (unsigned short)(r >> 16);
}

// out[rows,64](bf16) = act(in[rows,K] @ W[K,64] (+ bias)), MFMA 16x16x32 bf16, f32 accum.
// AF32: input is f32 (converted in-register); else input is bf16.
template <int K, bool AF32, bool BIAS, bool ACT>
__global__ __launch_bounds__(256) void mfma_gemm(
    const void* __restrict__ in_v, const float* __restrict__ W,
    const float* __restrict__ bias, unsigned short* __restrict__ out, int rows)
{
    constexpr int S = K / 32;              // k-steps
    __shared__ short8 WL[4 * S * 64];      // B-frags pre-permuted: [coltile][step][lane]

    // stage W (f32, row-major K x 64) into fragment-ordered bf16 LDS
    for (int f = threadIdx.x; f < 4 * S * 64; f += 256) {
        int c = f / (S * 64);
        int rem = f % (S * 64);
        int s = rem / 64;
        int l = rem % 64;
        short8 frag;
        #pragma unroll
        for (int j = 0; j < 8; ++j) {
            int k = s * 32 + (l >> 4) * 8 + j;
            int col = c * 16 + (l & 15);
            frag[j] = (short)f2b(W[k * H + col]);
        }
        WL[f] = frag;
    }
    __syncthreads();

    const int l = threadIdx.x & 63;
    const int wv = threadIdx.x >> 6;
    const int rowBase = blockIdx.x * 64 + wv * 16;
    if (rowBase >= rows) return;
    const int arow = min(rowBase + (l & 15), rows - 1);

    floatx4 acc0 = {0.f, 0.f, 0.f, 0.f};
    floatx4 acc1 = {0.f, 0.f, 0.f, 0.f};
    floatx4 acc2 = {0.f, 0.f, 0.f, 0.f};
    floatx4 acc3 = {0.f, 0.f, 0.f, 0.f};

    #pragma unroll
    for (int s = 0; s < S; ++s) {
        short8 a;
        if (AF32) {
            const float* ap = (const float*)in_v + (size_t)arow * K + s * 32 + (l >> 4) * 8;
            float4 f0 = *(const float4*)(ap + 0);
            float4 f1 = *(const float4*)(ap + 4);
            a[0] = (short)f2b(f0.x); a[1] = (short)f2b(f0.y);
            a[2] = (short)f2b(f0.z); a[3] = (short)f2b(f0.w);
            a[4] = (short)f2b(f1.x); a[5] = (short)f2b(f1.y);
            a[6] = (short)f2b(f1.z); a[7] = (short)f2b(f1.w);
        } else {
            a = *(const short8*)((const unsigned short*)in_v + (size_t)arow * K + s * 32 + (l >> 4) * 8);
        }
        acc0 = __builtin_amdgcn_mfma_f32_16x16x32_bf16(a, WL[(0 * S + s) * 64 + l], acc0, 0, 0, 0);
        acc1 = __builtin_amdgcn_mfma_f32_16x16x32_bf16(a, WL[(1 * S + s) * 64 + l], acc1, 0, 0, 0);
        acc2 = __builtin_amdgcn_mfma_f32_16x16x32_bf16(a, WL[(2 * S + s) * 64 + l], acc2, 0, 0, 0);
        acc3 = __builtin_amdgcn_mfma_f32_16x16x32_bf16(a, WL[(3 * S + s) * 64 + l], acc3, 0, 0, 0);
    }

    // D layout: col = c*16 + (l&15), row = rowBase + (l>>4)*4 + j
    #pragma unroll
    for (int j = 0; j < 4; ++j) {
        int row = rowBase + (l >> 4) * 4 + j;
        if (row >= rows) continue;
        unsigned short* orow = out + (size_t)row * H;
        float v;
        int col = l & 15;
        v = acc0[j] + (BIAS ? bias[col] : 0.f);      if (ACT) v = lrelu(v); orow[col] = f2b(v);
        v = acc1[j] + (BIAS ? bias[col + 16] : 0.f); if (ACT) v = lrelu(v); orow[col + 16] = f2b(v);
        v = acc2[j] + (BIAS ? bias[col + 32] : 0.f); if (ACT) v = lrelu(v); orow[col + 32] = f2b(v);
        v = acc3[j] + (BIAS ? bias[col + 48] : 0.f); if (ACT) v = lrelu(v); orow[col + 48] = f2b(v);
    }
}

// ---------------- CSR build ----------------

__global__ __launch_bounds__(256) void zero_i(int* __restrict__ p, int n)
{
    int i = blockIdx.x * 256 + threadIdx.x;
    if (i < n) p[i] = 0;
}

__global__ __launch_bounds__(256) void count_edges(const int* __restrict__ dst, int* __restrict__ cnt, int nE)
{
    int i = blockIdx.x * 256 + threadIdx.x;
    if (i < nE) atomicAdd(&cnt[dst[i]], 1);
}

__global__ __launch_bounds__(256) void scan1(const int* __restrict__ cnt, int* __restrict__ rs,
                                             int* __restrict__ bsum, int n)
{
    __shared__ int lds[256];
    int t = threadIdx.x;
    int base = blockIdx.x * 1024 + t * 4;
    int v0 = 0, v1 = 0, v2 = 0, v3 = 0;
    if (base + 0 < n) v0 = cnt[base + 0];
    if (base + 1 < n) v1 = cnt[base + 1];
    if (base + 2 < n) v2 = cnt[base + 2];
    if (base + 3 < n) v3 = cnt[base + 3];
    int s = v0 + v1 + v2 + v3;
    lds[t] = s;
    __syncthreads();
    for (int off = 1; off < 256; off <<= 1) {
        int y = (t >= off) ? lds[t - off] : 0;
        __syncthreads();
        lds[t] += y;
        __syncthreads();
    }
    int excl = lds[t] - s;
    if (base + 0 < n) rs[base + 0] = excl;
    if (base + 1 < n) rs[base + 1] = excl + v0;
    if (base + 2 < n) rs[base + 2] = excl + v0 + v1;
    if (base + 3 < n) rs[base + 3] = excl + v0 + v1 + v2;
    if (t == 255) bsum[blockIdx.x] = lds[255];
}

__global__ __launch_bounds__(256) void scan2(int* __restrict__ bsum, int nb)
{
    __shared__ int lds[256];
    int t = threadIdx.x;
    int v = (t < nb) ? bsum[t] : 0;
    lds[t] = v;
    __syncthreads();
    for (int off = 1; off < 256; off <<= 1) {
        int y = (t >= off) ? lds[t - off] : 0;
        __syncthreads();
        lds[t] += y;
        __syncthreads();
    }
    if (t < nb) bsum[t] = lds[t] - v;
}

__global__ __launch_bounds__(256) void scan3(int* __restrict__ rs, int* __restrict__ cur,
                                             const int* __restrict__ bsum, int n)
{
    int i = blockIdx.x * 256 + threadIdx.x;
    if (i < n) {
        int r = rs[i] + bsum[i >> 10];
        rs[i] = r;
        cur[i] = r;
    }
}

__global__ __launch_bounds__(256) void fill_edges(const int* __restrict__ src, const int* __restrict__ dst,
                                                  int* __restrict__ cur, int* __restrict__ esrc, int nE)
{
    int e = blockIdx.x * 256 + threadIdx.x;
    if (e < nE) {
        int pos = atomicAdd(&cur[dst[e]], 1);
        esrc[pos] = src[e];
    }
}

__global__ __launch_bounds__(256) void mkdis(const int* __restrict__ cnt, float* __restrict__ dis,
                                             int n, int selfadd)
{
    int i = blockIdx.x * 256 + threadIdx.x;
    if (i < n) {
        int d = cnt[i] + selfadd;
        dis[i] = d > 0 ? rsqrtf((float)d) : 0.0f;
    }
}

// out[d] = lrelu( dis[d]*sum_e h[src_e]*dis[src_e] (+ h[d]*dis[d]^2 if SELF) + bias ), bf16 h/out
template <bool SELF>
__global__ __launch_bounds__(256) void gather(const unsigned short* __restrict__ h,
                                              const int* __restrict__ esrc,
                                              const int* __restrict__ rs, const int* __restrict__ cnt,
                                              const float* __restrict__ dis, const float* __restrict__ bias,
                                              unsigned short* __restrict__ out, int n)
{
    int d = blockIdx.x * 4 + (threadIdx.x >> 6);
    if (d >= n) return;
    int lane = threadIdx.x & 63;
    int beg = rs[d];
    int c = cnt[d];
    float dd = dis[d];
    float a0 = 0.f, a1 = 0.f;
    int i = 0;
    for (; i + 2 <= c; i += 2) {
        int s0 = esrc[beg + i], s1 = esrc[beg + i + 1];
        float w0 = dis[s0], w1 = dis[s1];
        a0 += b2f(h[(size_t)s0 * H + lane]) * w0;
        a1 += b2f(h[(size_t)s1 * H + lane]) * w1;
    }
    if (i < c) {
        int s = esrc[beg + i];
        a0 += b2f(h[(size_t)s * H + lane]) * dis[s];
    }
    float r = (a0 + a1) * dd;
    if (SELF) r += b2f(h[(size_t)d * H + lane]) * dd * dd;
    out[(size_t)d * H + lane] = f2b(lrelu(r + bias[lane]));
}

// logits = z @ Wc + bc  (C=2), then log_softmax; one wave per row; z is bf16
__global__ __launch_bounds__(256) void classifier(const unsigned short* __restrict__ z,
                                                  const float* __restrict__ Wc,
                                                  const float* __restrict__ bc, float* __restrict__ out, int n)
{
    int row = blockIdx.x * 4 + (threadIdx.x >> 6);
    if (row >= n) return;
    int lane = threadIdx.x & 63;
    float v = b2f(z[(size_t)row * H + lane]);
    float p0 = v * Wc[lane * 2 + 0];
    float p1 = v * Wc[lane * 2 + 1];
    #pragma unroll
    for (int off = 32; off; off >>= 1) {
        p0 += __shfl_xor(p0, off);
        p1 += __shfl_xor(p1, off);
    }
    if (lane == 0) {
        float l0 = p0 + bc[0], l1 = p1 + bc[1];
        float m = fmaxf(l0, l1);
        float lse = m + logf(expf(l0 - m) + expf(l1 - m));
        out[(size_t)row * 2 + 0] = l0 - lse;
        out[(size_t)row * 2 + 1] = l1 - lse;
    }
}

extern "C" void kernel_launch(void* const* d_in, const int* in_sizes, int n_in,
                              void* d_out, int out_size, void* d_ws, size_t ws_size,
                              hipStream_t stream)
{
    const float* x      = (const float*)d_in[0];
    const int*   ei     = (const int*)d_in[1];
    const float* mx     = (const float*)d_in[2];
    const int*   mei    = (const int*)d_in[3];
    const float* W_lin  = (const float*)d_in[4];
    const float* b_lin  = (const float*)d_in[5];
    const float* W_mlin = (const float*)d_in[6];
    const float* b_mlin = (const float*)d_in[7];
    const float* W0     = (const float*)d_in[8];
    const float* b0     = (const float*)d_in[9];
    const float* W1     = (const float*)d_in[10];
    const float* b1     = (const float*)d_in[11];
    const float* Wm     = (const float*)d_in[12];
    const float* bm     = (const float*)d_in[13];
    const float* Wc     = (const float*)d_in[14];
    const float* bc     = (const float*)d_in[15];

    const int F  = 128;
    const int N  = in_sizes[0] / F;
    const int E  = in_sizes[1] / 2;
    const int M  = in_sizes[2] / F;
    const int Em = in_sizes[3] / 2;
    const int NM = N + M;
    const int* src  = ei;
    const int* dstp = ei + E;
    const int* msrc = mei;
    const int* mdst = mei + Em;
    const int Emax = E > Em ? E : Em;

    unsigned short* hb0 = (unsigned short*)d_ws;        // [NM, H] bf16
    unsigned short* hb1 = hb0 + (size_t)NM * H;         // [NM, H] bf16
    float* dis = (float*)(hb1 + (size_t)NM * H);        // [NM]
    int*   cnt  = (int*)(dis + NM);                     // [NM]
    int*   rs   = cnt + NM;                             // [NM]
    int*   cur  = rs + NM;                              // [NM]
    int*   esrc = cur + NM;                             // [Emax]
    int*   bsum = esrc + Emax;                          // [<=256]

    // input projections (meta rows written straight into concat slot)
    mfma_gemm<128, true, true, true><<<(N + 63) / 64, 256, 0, stream>>>(x, W_lin, b_lin, hb0, N);
    mfma_gemm<128, true, true, true><<<(M + 63) / 64, 256, 0, stream>>>(mx, W_mlin, b_mlin, hb0 + (size_t)N * H, M);

    // data-graph CSR (reused by both GCN layers)
    const int nb1 = (N + 1023) / 1024;
    zero_i<<<(N + 255) / 256, 256, 0, stream>>>(cnt, N);
    count_edges<<<(E + 255) / 256, 256, 0, stream>>>(dstp, cnt, E);
    scan1<<<nb1, 256, 0, stream>>>(cnt, rs, bsum, N);
    scan2<<<1, 256, 0, stream>>>(bsum, nb1);
    scan3<<<(N + 255) / 256, 256, 0, stream>>>(rs, cur, bsum, N);
    fill_edges<<<(E + 255) / 256, 256, 0, stream>>>(src, dstp, cur, esrc, E);
    mkdis<<<(N + 255) / 256, 256, 0, stream>>>(cnt, dis, N, 1);

    // GCN layer 0
    mfma_gemm<64, false, false, false><<<(N + 63) / 64, 256, 0, stream>>>(hb0, W0, nullptr, hb1, N);
    gather<true><<<(N + 3) / 4, 256, 0, stream>>>(hb1, esrc, rs, cnt, dis, b0, hb0, N);

    // GCN layer 1
    mfma_gemm<64, false, false, false><<<(N + 63) / 64, 256, 0, stream>>>(hb0, W1, nullptr, hb1, N);
    gather<true><<<(N + 3) / 4, 256, 0, stream>>>(hb1, esrc, rs, cnt, dis, b1, hb0, N);

    // meta fusion over z = hb0[0..NM)
    mfma_gemm<64, false, false, false><<<(NM + 63) / 64, 256, 0, stream>>>(hb0, Wm, nullptr, hb1, NM);

    const int nb2 = (NM + 1023) / 1024;
    zero_i<<<(NM + 255) / 256, 256, 0, stream>>>(cnt, NM);
    count_edges<<<(Em + 255) / 256, 256, 0, stream>>>(mdst, cnt, Em);
    scan1<<<nb2, 256, 0, stream>>>(cnt, rs, bsum, NM);
    scan2<<<1, 256, 0, stream>>>(bsum, nb2);
    scan3<<<(NM + 255) / 256, 256, 0, stream>>>(rs, cur, bsum, NM);
    fill_edges<<<(Em + 255) / 256, 256, 0, stream>>>(msrc, mdst, cur, esrc, Em);
    mkdis<<<(NM + 255) / 256, 256, 0, stream>>>(cnt, dis, NM, 0);

    gather<false><<<(NM + 3) / 4, 256, 0, stream>>>(hb1, esrc, rs, cnt, dis, bm, hb0, NM);

    // classifier + log_softmax
    classifier<<<(NM + 3) / 4, 256, 0, stream>>>(hb0, Wc, bc, (float*)d_out, NM);
}

// Round 4
// 365.198 us; speedup vs baseline: 3.3816x; 1.5404x over previous
//
#include <hip/hip_runtime.h>
#include <cstddef>

static constexpr float ALPHA = 0.2f;
static constexpr int H = 64;
static constexpr int TILE = 10240;   // bfill edges per block
static constexpr int NBMAX = 1024;   // max buckets (128 nodes each -> up to 131072 nodes)

typedef __attribute__((ext_vector_type(8))) short short8;
typedef __attribute__((ext_vector_type(4))) float floatx4;

__device__ __forceinline__ float lrelu(float v) { return v >= 0.0f ? v : ALPHA * v; }

__device__ __forceinline__ float b2f(unsigned short u)
{
    union { unsigned int i; float f; } x;
    x.i = ((unsigned int)u) << 16;
    return x.f;
}

__device__ __forceinline__ unsigned short f2b(float f)
{
    union { float f; unsigned int i; } x;
    x.f = f;
    unsigned int r = x.i + 0x7fffu + ((x.i >> 16) & 1u);  // RNE
    return (unsigned short)(r >> 16);
}

// ---------------- MFMA GEMM: out[rows,64](bf16) = act(in[rows,K] @ W[K,64] (+bias)) ----------------
template <int K, bool AF32, bool BIAS, bool ACT>
__global__ __launch_bounds__(256) void mfma_gemm(
    const void* __restrict__ in_v, const float* __restrict__ W,
    const float* __restrict__ bias, unsigned short* __restrict__ out, int rows)
{
    constexpr int S = K / 32;
    __shared__ short8 WL[4 * S * 64];

    for (int f = threadIdx.x; f < 4 * S * 64; f += 256) {
        int c = f / (S * 64);
        int rem = f % (S * 64);
        int s = rem / 64;
        int l = rem % 64;
        short8 frag;
        #pragma unroll
        for (int j = 0; j < 8; ++j) {
            int k = s * 32 + (l >> 4) * 8 + j;
            int col = c * 16 + (l & 15);
            frag[j] = (short)f2b(W[k * H + col]);
        }
        WL[f] = frag;
    }
    __syncthreads();

    const int l = threadIdx.x & 63;
    const int wv = threadIdx.x >> 6;
    const int rowBase = blockIdx.x * 64 + wv * 16;
    if (rowBase >= rows) return;
    const int arow = min(rowBase + (l & 15), rows - 1);

    floatx4 acc0 = {0.f, 0.f, 0.f, 0.f};
    floatx4 acc1 = {0.f, 0.f, 0.f, 0.f};
    floatx4 acc2 = {0.f, 0.f, 0.f, 0.f};
    floatx4 acc3 = {0.f, 0.f, 0.f, 0.f};

    #pragma unroll
    for (int s = 0; s < S; ++s) {
        short8 a;
        if (AF32) {
            const float* ap = (const float*)in_v + (size_t)arow * K + s * 32 + (l >> 4) * 8;
            float4 f0 = *(const float4*)(ap + 0);
            float4 f1 = *(const float4*)(ap + 4);
            a[0] = (short)f2b(f0.x); a[1] = (short)f2b(f0.y);
            a[2] = (short)f2b(f0.z); a[3] = (short)f2b(f0.w);
            a[4] = (short)f2b(f1.x); a[5] = (short)f2b(f1.y);
            a[6] = (short)f2b(f1.z); a[7] = (short)f2b(f1.w);
        } else {
            a = *(const short8*)((const unsigned short*)in_v + (size_t)arow * K + s * 32 + (l >> 4) * 8);
        }
        acc0 = __builtin_amdgcn_mfma_f32_16x16x32_bf16(a, WL[(0 * S + s) * 64 + l], acc0, 0, 0, 0);
        acc1 = __builtin_amdgcn_mfma_f32_16x16x32_bf16(a, WL[(1 * S + s) * 64 + l], acc1, 0, 0, 0);
        acc2 = __builtin_amdgcn_mfma_f32_16x16x32_bf16(a, WL[(2 * S + s) * 64 + l], acc2, 0, 0, 0);
        acc3 = __builtin_amdgcn_mfma_f32_16x16x32_bf16(a, WL[(3 * S + s) * 64 + l], acc3, 0, 0, 0);
    }

    #pragma unroll
    for (int j = 0; j < 4; ++j) {
        int row = rowBase + (l >> 4) * 4 + j;
        if (row >= rows) continue;
        unsigned short* orow = out + (size_t)row * H;
        float v;
        int col = l & 15;
        v = acc0[j] + (BIAS ? bias[col] : 0.f);      if (ACT) v = lrelu(v); orow[col] = f2b(v);
        v = acc1[j] + (BIAS ? bias[col + 16] : 0.f); if (ACT) v = lrelu(v); orow[col + 16] = f2b(v);
        v = acc2[j] + (BIAS ? bias[col + 32] : 0.f); if (ACT) v = lrelu(v); orow[col + 32] = f2b(v);
        v = acc3[j] + (BIAS ? bias[col + 48] : 0.f); if (ACT) v = lrelu(v); orow[col + 48] = f2b(v);
    }
}

// ---------------- bucket-sort CSR build ----------------

__global__ __launch_bounds__(256) void zero_i(int* __restrict__ p, int n)
{
    int i = blockIdx.x * 256 + threadIdx.x;
    if (i < n) p[i] = 0;
}

// LDS-aggregated histogram of dst>>7
__global__ __launch_bounds__(256) void bhist(const int* __restrict__ dst, int* __restrict__ gbh,
                                             int nE, int nb)
{
    __shared__ int lh[NBMAX];
    for (int i = threadIdx.x; i < nb; i += 256) lh[i] = 0;
    __syncthreads();
    for (int i = blockIdx.x * 256 + threadIdx.x; i < nE; i += 256 * gridDim.x)
        atomicAdd(&lh[dst[i] >> 7], 1);
    __syncthreads();
    for (int b = threadIdx.x; b < nb; b += 256) {
        int v = lh[b];
        if (v) atomicAdd(&gbh[b], v);
    }
}

// single-block exclusive scan of gbh -> goff and gcur (nb <= 1024)
__global__ __launch_bounds__(256) void bscan(const int* __restrict__ gbh, int* __restrict__ goff,
                                             int* __restrict__ gcur, int nb)
{
    __shared__ int sp[256];
    int t = threadIdx.x;
    int base = t * 4;
    int a0 = base + 0 < nb ? gbh[base + 0] : 0;
    int a1 = base + 1 < nb ? gbh[base + 1] : 0;
    int a2 = base + 2 < nb ? gbh[base + 2] : 0;
    int a3 = base + 3 < nb ? gbh[base + 3] : 0;
    int s = a0 + a1 + a2 + a3;
    sp[t] = s;
    __syncthreads();
    for (int o = 1; o < 256; o <<= 1) {
        int y = (t >= o) ? sp[t - o] : 0;
        __syncthreads();
        sp[t] += y;
        __syncthreads();
    }
    int e = sp[t] - s;
    if (base + 0 < nb) { goff[base + 0] = e;                gcur[base + 0] = e; }
    if (base + 1 < nb) { goff[base + 1] = e + a0;           gcur[base + 1] = e + a0; }
    if (base + 2 < nb) { goff[base + 2] = e + a0 + a1;      gcur[base + 2] = e + a0 + a1; }
    if (base + 3 < nb) { goff[base + 3] = e + a0 + a1 + a2; gcur[base + 3] = e + a0 + a1 + a2; }
}

// per-tile: LDS bucket sort, then contiguous-run copy-out into global bucket segments.
// packed entry = (dstLocal<<17) | src   (src < 2^17, dstLocal < 128)
__global__ __launch_bounds__(256) void bfill(const int* __restrict__ src, const int* __restrict__ dst,
                                             int* __restrict__ gcur, int* __restrict__ ebuf,
                                             int nE, int nb)
{
    __shared__ int pk[TILE];
    __shared__ int lh[NBMAX];
    __shared__ int lc[NBMAX];
    __shared__ int grv[NBMAX];
    __shared__ int sp[256];

    const int t = threadIdx.x;
    const int base = blockIdx.x * TILE;
    const int nT = min(TILE, nE - base);

    for (int i = t; i < nb; i += 256) lh[i] = 0;
    __syncthreads();
    for (int i = t; i < nT; i += 256) atomicAdd(&lh[dst[base + i] >> 7], 1);
    __syncthreads();

    // exclusive scan lh -> lc (4 per thread)
    {
        int b4 = t * 4;
        int a0 = b4 + 0 < nb ? lh[b4 + 0] : 0;
        int a1 = b4 + 1 < nb ? lh[b4 + 1] : 0;
        int a2 = b4 + 2 < nb ? lh[b4 + 2] : 0;
        int a3 = b4 + 3 < nb ? lh[b4 + 3] : 0;
        int s = a0 + a1 + a2 + a3;
        sp[t] = s;
        __syncthreads();
        for (int o = 1; o < 256; o <<= 1) {
            int y = (t >= o) ? sp[t - o] : 0;
            __syncthreads();
            sp[t] += y;
            __syncthreads();
        }
        int e = sp[t] - s;
        if (b4 + 0 < nb) lc[b4 + 0] = e;
        if (b4 + 1 < nb) lc[b4 + 1] = e + a0;
        if (b4 + 2 < nb) lc[b4 + 2] = e + a0 + a1;
        if (b4 + 3 < nb) lc[b4 + 3] = e + a0 + a1 + a2;
    }
    __syncthreads();

    // LDS scatter (lc becomes inclusive ends afterwards)
    for (int i = t; i < nT; i += 256) {
        int d = dst[base + i];
        int b = d >> 7;
        int pos = atomicAdd(&lc[b], 1);
        pk[pos] = ((d & 127) << 17) | src[base + i];
    }
    __syncthreads();

    // reserve global space per bucket
    for (int b = t; b < nb; b += 256) {
        int k = lh[b];
        grv[b] = k ? atomicAdd(&gcur[b], k) : 0;
    }
    __syncthreads();

    // copy-out: position i -> bucket via binary search on ends; contiguous runs per bucket
    for (int i = t; i < nT; i += 256) {
        int lo = 0, hi = nb;
        while (lo < hi) {
            int mid = (lo + hi) >> 1;
            if (lc[mid] > i) hi = mid; else lo = mid + 1;
        }
        int b = lo;
        int start = lc[b] - lh[b];
        ebuf[grv[b] + (i - start)] = pk[i];
    }
}

// block per bucket: local counting sort -> esrc (dense), rs/cnt/dis for 128 nodes
__global__ __launch_bounds__(256) void local_csr(const int* __restrict__ ebuf, const int* __restrict__ goff,
                                                 const int* __restrict__ gbh, int* __restrict__ esrc,
                                                 int* __restrict__ rs, int* __restrict__ cnt,
                                                 float* __restrict__ dis, int n, int selfadd)
{
    __shared__ int lcnt[128];
    __shared__ int lrs[128];
    __shared__ int lcur[128];
    const int b = blockIdx.x;
    const int t = threadIdx.x;
    const int off = goff[b];
    const int k = gbh[b];

    if (t < 128) lcnt[t] = 0;
    __syncthreads();
    for (int i = t; i < k; i += 256) atomicAdd(&lcnt[ebuf[off + i] >> 17], 1);
    __syncthreads();
    if (t < 128) lrs[t] = lcnt[t];
    __syncthreads();
    for (int o = 1; o < 128; o <<= 1) {
        int y = (t < 128 && t >= o) ? lrs[t - o] : 0;
        __syncthreads();
        if (t < 128) lrs[t] += y;
        __syncthreads();
    }
    if (t < 128) lcur[t] = lrs[t] - lcnt[t];   // exclusive
    __syncthreads();
    for (int i = t; i < k; i += 256) {
        int v = ebuf[off + i];
        int dL = v >> 17;
        int pos = atomicAdd(&lcur[dL], 1);
        esrc[off + pos] = v & 0x1FFFF;
    }
    int node = b * 128 + t;
    if (t < 128 && node < n) {
        int c = lcnt[t];
        rs[node] = off + (lrs[t] - c);
        cnt[node] = c;
        int dt = c + selfadd;
        dis[node] = dt > 0 ? rsqrtf((float)dt) : 0.0f;
    }
}

// ---------------- gather (16 lanes per dst row, ushort4 loads) ----------------
// SELF: add h[d]*dis[d]^2 (implicit self loop). FINAL: fuse classifier+log_softmax, no bf16 out.
template <bool SELF, bool FINAL>
__global__ __launch_bounds__(256) void gather16(const unsigned short* __restrict__ h,
                                                const int* __restrict__ esrc,
                                                const int* __restrict__ rs, const int* __restrict__ cnt,
                                                const float* __restrict__ dis, const float* __restrict__ bias,
                                                unsigned short* __restrict__ out,
                                                const float* __restrict__ Wc, const float* __restrict__ bc,
                                                float* __restrict__ fout, int n)
{
    int d = blockIdx.x * 16 + (threadIdx.x >> 4);
    if (d >= n) return;
    const int l = threadIdx.x & 15;
    const int beg = rs[d];
    const int c = cnt[d];
    const float dd = dis[d];

    float ax0 = 0.f, ay0 = 0.f, az0 = 0.f, aw0 = 0.f;
    float ax1 = 0.f, ay1 = 0.f, az1 = 0.f, aw1 = 0.f;
    int i = 0;
    for (; i + 2 <= c; i += 2) {
        int s0 = esrc[beg + i], s1 = esrc[beg + i + 1];
        float w0 = dis[s0], w1 = dis[s1];
        ushort4 v0 = *(const ushort4*)(h + (size_t)s0 * H + l * 4);
        ushort4 v1 = *(const ushort4*)(h + (size_t)s1 * H + l * 4);
        ax0 += w0 * b2f(v0.x); ay0 += w0 * b2f(v0.y); az0 += w0 * b2f(v0.z); aw0 += w0 * b2f(v0.w);
        ax1 += w1 * b2f(v1.x); ay1 += w1 * b2f(v1.y); az1 += w1 * b2f(v1.z); aw1 += w1 * b2f(v1.w);
    }
    if (i < c) {
        int s = esrc[beg + i];
        float w = dis[s];
        ushort4 v = *(const ushort4*)(h + (size_t)s * H + l * 4);
        ax0 += w * b2f(v.x); ay0 += w * b2f(v.y); az0 += w * b2f(v.z); aw0 += w * b2f(v.w);
    }

    float rx = (ax0 + ax1) * dd, ry = (ay0 + ay1) * dd, rz = (az0 + az1) * dd, rw = (aw0 + aw1) * dd;
    if (SELF) {
        ushort4 v = *(const ushort4*)(h + (size_t)d * H + l * 4);
        float s2 = dd * dd;
        rx += s2 * b2f(v.x); ry += s2 * b2f(v.y); rz += s2 * b2f(v.z); rw += s2 * b2f(v.w);
    }
    float4 bb = *(const float4*)(bias + l * 4);
    rx = lrelu(rx + bb.x); ry = lrelu(ry + bb.y); rz = lrelu(rz + bb.z); rw = lrelu(rw + bb.w);

    if (FINAL) {
        // logits = z @ Wc + bc over the 16-lane group, then log_softmax
        int f = l * 4;
        float p0 = rx * Wc[(f + 0) * 2] + ry * Wc[(f + 1) * 2] + rz * Wc[(f + 2) * 2] + rw * Wc[(f + 3) * 2];
        float p1 = rx * Wc[(f + 0) * 2 + 1] + ry * Wc[(f + 1) * 2 + 1] + rz * Wc[(f + 2) * 2 + 1] + rw * Wc[(f + 3) * 2 + 1];
        #pragma unroll
        for (int o = 8; o; o >>= 1) {
            p0 += __shfl_xor(p0, o);
            p1 += __shfl_xor(p1, o);
        }
        if (l == 0) {
            float l0 = p0 + bc[0], l1 = p1 + bc[1];
            float m = fmaxf(l0, l1);
            float lse = m + logf(expf(l0 - m) + expf(l1 - m));
            fout[(size_t)d * 2 + 0] = l0 - lse;
            fout[(size_t)d * 2 + 1] = l1 - lse;
        }
    } else {
        ushort4 o;
        o.x = f2b(rx); o.y = f2b(ry); o.z = f2b(rz); o.w = f2b(rw);
        *(ushort4*)(out + (size_t)d * H + l * 4) = o;
    }
}

extern "C" void kernel_launch(void* const* d_in, const int* in_sizes, int n_in,
                              void* d_out, int out_size, void* d_ws, size_t ws_size,
                              hipStream_t stream)
{
    const float* x      = (const float*)d_in[0];
    const int*   ei     = (const int*)d_in[1];
    const float* mx     = (const float*)d_in[2];
    const int*   mei    = (const int*)d_in[3];
    const float* W_lin  = (const float*)d_in[4];
    const float* b_lin  = (const float*)d_in[5];
    const float* W_mlin = (const float*)d_in[6];
    const float* b_mlin = (const float*)d_in[7];
    const float* W0     = (const float*)d_in[8];
    const float* b0     = (const float*)d_in[9];
    const float* W1     = (const float*)d_in[10];
    const float* b1     = (const float*)d_in[11];
    const float* Wm     = (const float*)d_in[12];
    const float* bm     = (const float*)d_in[13];
    const float* Wc     = (const float*)d_in[14];
    const float* bc     = (const float*)d_in[15];

    const int F  = 128;
    const int N  = in_sizes[0] / F;
    const int E  = in_sizes[1] / 2;
    const int M  = in_sizes[2] / F;
    const int Em = in_sizes[3] / 2;
    const int NM = N + M;
    const int* src  = ei;
    const int* dstp = ei + E;
    const int* msrc = mei;
    const int* mdst = mei + Em;
    const int Emax = E > Em ? E : Em;

    unsigned short* hb0 = (unsigned short*)d_ws;        // [NM, H] bf16
    unsigned short* hb1 = hb0 + (size_t)NM * H;         // [NM, H] bf16
    float* dis = (float*)(hb1 + (size_t)NM * H);        // [NM]
    int*   cnt  = (int*)(dis + NM);                     // [NM]
    int*   rs   = cnt + NM;                             // [NM]
    int*   ebuf = rs + NM;                              // [Emax]
    int*   esrc = ebuf + Emax;                          // [Emax]
    int*   gbh  = esrc + Emax;                          // [NBMAX]
    int*   goff = gbh + NBMAX;                          // [NBMAX]
    int*   gcur = goff + NBMAX;                         // [NBMAX]

    const int nbD = (N + 127) / 128;
    const int nbM = (NM + 127) / 128;

    // input projections (meta rows go straight to concat slot)
    mfma_gemm<128, true, true, true><<<(N + 63) / 64, 256, 0, stream>>>(x, W_lin, b_lin, hb0, N);
    mfma_gemm<128, true, true, true><<<(M + 63) / 64, 256, 0, stream>>>(mx, W_mlin, b_mlin, hb0 + (size_t)N * H, M);

    // data-graph CSR (reused by both GCN layers)
    zero_i<<<(NBMAX + 255) / 256, 256, 0, stream>>>(gbh, NBMAX);
    bhist<<<min(256, (E + 255) / 256), 256, 0, stream>>>(dstp, gbh, E, nbD);
    bscan<<<1, 256, 0, stream>>>(gbh, goff, gcur, nbD);
    bfill<<<(E + TILE - 1) / TILE, 256, 0, stream>>>(src, dstp, gcur, ebuf, E, nbD);
    local_csr<<<nbD, 256, 0, stream>>>(ebuf, goff, gbh, esrc, rs, cnt, dis, N, 1);

    // GCN layer 0
    mfma_gemm<64, false, false, false><<<(N + 63) / 64, 256, 0, stream>>>(hb0, W0, nullptr, hb1, N);
    gather16<true, false><<<(N + 15) / 16, 256, 0, stream>>>(hb1, esrc, rs, cnt, dis, b0, hb0, nullptr, nullptr, nullptr, N);

    // GCN layer 1
    mfma_gemm<64, false, false, false><<<(N + 63) / 64, 256, 0, stream>>>(hb0, W1, nullptr, hb1, N);
    gather16<true, false><<<(N + 15) / 16, 256, 0, stream>>>(hb1, esrc, rs, cnt, dis, b1, hb0, nullptr, nullptr, nullptr, N);

    // meta fusion GEMM over z = hb0[0..NM)
    mfma_gemm<64, false, false, false><<<(NM + 63) / 64, 256, 0, stream>>>(hb0, Wm, nullptr, hb1, NM);

    // meta-graph CSR
    zero_i<<<(NBMAX + 255) / 256, 256, 0, stream>>>(gbh, NBMAX);
    bhist<<<min(256, (Em + 255) / 256), 256, 0, stream>>>(mdst, gbh, Em, nbM);
    bscan<<<1, 256, 0, stream>>>(gbh, goff, gcur, nbM);
    bfill<<<(Em + TILE - 1) / TILE, 256, 0, stream>>>(msrc, mdst, gcur, ebuf, Em, nbM);
    local_csr<<<nbM, 256, 0, stream>>>(ebuf, goff, gbh, esrc, rs, cnt, dis, NM, 0);

    // final gather + fused classifier + log_softmax
    gather16<false, true><<<(NM + 15) / 16, 256, 0, stream>>>(hb1, esrc, rs, cnt, dis, bm, nullptr, Wc, bc, (float*)d_out, NM);
}

// Round 5
// 292.138 us; speedup vs baseline: 4.2273x; 1.2501x over previous
//
#include <hip/hip_runtime.h>
#include <cstddef>

static constexpr float ALPHA = 0.2f;
static constexpr int H = 64;
static constexpr int NBMAX = 1024;   // max buckets (128 nodes each)

typedef __attribute__((ext_vector_type(8))) short short8;
typedef __attribute__((ext_vector_type(4))) float floatx4;

__device__ __forceinline__ float lrelu(float v) { return v >= 0.0f ? v : ALPHA * v; }

__device__ __forceinline__ float b2f(unsigned short u)
{
    union { unsigned int i; float f; } x;
    x.i = ((unsigned int)u) << 16;
    return x.f;
}

__device__ __forceinline__ unsigned short f2b(float f)
{
    union { float f; unsigned int i; } x;
    x.f = f;
    unsigned int r = x.i + 0x7fffu + ((x.i >> 16) & 1u);  // RNE
    return (unsigned short)(r >> 16);
}

// ---- MFMA GEMM: out[rows,64](bf16) = act(in[rows,K] @ W[K,64] (+bias)) (* scl[row]) ----
template <int K, bool AF32, bool BIAS, bool ACT, bool SCALE>
__global__ __launch_bounds__(256) void mfma_gemm(
    const void* __restrict__ in_v, const float* __restrict__ W,
    const float* __restrict__ bias, const float* __restrict__ scl,
    unsigned short* __restrict__ out, int rows)
{
    constexpr int S = K / 32;
    __shared__ short8 WL[4 * S * 64];

    for (int f = threadIdx.x; f < 4 * S * 64; f += 256) {
        int c = f / (S * 64);
        int rem = f % (S * 64);
        int s = rem / 64;
        int l = rem % 64;
        short8 frag;
        #pragma unroll
        for (int j = 0; j < 8; ++j) {
            int k = s * 32 + (l >> 4) * 8 + j;
            int col = c * 16 + (l & 15);
            frag[j] = (short)f2b(W[k * H + col]);
        }
        WL[f] = frag;
    }
    __syncthreads();

    const int l = threadIdx.x & 63;
    const int wv = threadIdx.x >> 6;
    const int rowBase = blockIdx.x * 64 + wv * 16;
    if (rowBase >= rows) return;
    const int arow = min(rowBase + (l & 15), rows - 1);

    floatx4 acc0 = {0.f, 0.f, 0.f, 0.f};
    floatx4 acc1 = {0.f, 0.f, 0.f, 0.f};
    floatx4 acc2 = {0.f, 0.f, 0.f, 0.f};
    floatx4 acc3 = {0.f, 0.f, 0.f, 0.f};

    #pragma unroll
    for (int s = 0; s < S; ++s) {
        short8 a;
        if (AF32) {
            const float* ap = (const float*)in_v + (size_t)arow * K + s * 32 + (l >> 4) * 8;
            float4 f0 = *(const float4*)(ap + 0);
            float4 f1 = *(const float4*)(ap + 4);
            a[0] = (short)f2b(f0.x); a[1] = (short)f2b(f0.y);
            a[2] = (short)f2b(f0.z); a[3] = (short)f2b(f0.w);
            a[4] = (short)f2b(f1.x); a[5] = (short)f2b(f1.y);
            a[6] = (short)f2b(f1.z); a[7] = (short)f2b(f1.w);
        } else {
            a = *(const short8*)((const unsigned short*)in_v + (size_t)arow * K + s * 32 + (l >> 4) * 8);
        }
        acc0 = __builtin_amdgcn_mfma_f32_16x16x32_bf16(a, WL[(0 * S + s) * 64 + l], acc0, 0, 0, 0);
        acc1 = __builtin_amdgcn_mfma_f32_16x16x32_bf16(a, WL[(1 * S + s) * 64 + l], acc1, 0, 0, 0);
        acc2 = __builtin_amdgcn_mfma_f32_16x16x32_bf16(a, WL[(2 * S + s) * 64 + l], acc2, 0, 0, 0);
        acc3 = __builtin_amdgcn_mfma_f32_16x16x32_bf16(a, WL[(3 * S + s) * 64 + l], acc3, 0, 0, 0);
    }

    #pragma unroll
    for (int j = 0; j < 4; ++j) {
        int row = rowBase + (l >> 4) * 4 + j;
        if (row >= rows) continue;
        unsigned short* orow = out + (size_t)row * H;
        float sc = SCALE ? scl[row] : 1.0f;
        float v;
        int col = l & 15;
        v = acc0[j] + (BIAS ? bias[col] : 0.f);      if (ACT) v = lrelu(v); orow[col]      = f2b(v * sc);
        v = acc1[j] + (BIAS ? bias[col + 16] : 0.f); if (ACT) v = lrelu(v); orow[col + 16] = f2b(v * sc);
        v = acc2[j] + (BIAS ? bias[col + 32] : 0.f); if (ACT) v = lrelu(v); orow[col + 32] = f2b(v * sc);
        v = acc3[j] + (BIAS ? bias[col + 48] : 0.f); if (ACT) v = lrelu(v); orow[col + 48] = f2b(v * sc);
    }
}

// ---------------- bucket-sort CSR build ----------------

__global__ __launch_bounds__(256) void zero_i(int* __restrict__ p, int n)
{
    int i = blockIdx.x * 256 + threadIdx.x;
    if (i < n) p[i] = 0;
}

__global__ __launch_bounds__(256) void bhist(const int* __restrict__ dst, int* __restrict__ gbh,
                                             int nE, int nb)
{
    __shared__ int lh[NBMAX];
    for (int i = threadIdx.x; i < nb; i += 256) lh[i] = 0;
    __syncthreads();
    for (int i = blockIdx.x * 256 + threadIdx.x; i < nE; i += 256 * gridDim.x)
        atomicAdd(&lh[dst[i] >> 7], 1);
    __syncthreads();
    for (int b = threadIdx.x; b < nb; b += 256) {
        int v = lh[b];
        if (v) atomicAdd(&gbh[b], v);
    }
}

__global__ __launch_bounds__(256) void bscan(const int* __restrict__ gbh, int* __restrict__ goff,
                                             int* __restrict__ gcur, int nb)
{
    __shared__ int sp[256];
    int t = threadIdx.x;
    int base = t * 4;
    int a0 = base + 0 < nb ? gbh[base + 0] : 0;
    int a1 = base + 1 < nb ? gbh[base + 1] : 0;
    int a2 = base + 2 < nb ? gbh[base + 2] : 0;
    int a3 = base + 3 < nb ? gbh[base + 3] : 0;
    int s = a0 + a1 + a2 + a3;
    sp[t] = s;
    __syncthreads();
    for (int o = 1; o < 256; o <<= 1) {
        int y = (t >= o) ? sp[t - o] : 0;
        __syncthreads();
        sp[t] += y;
        __syncthreads();
    }
    int e = sp[t] - s;
    if (base + 0 < nb) { goff[base + 0] = e;                gcur[base + 0] = e; }
    if (base + 1 < nb) { goff[base + 1] = e + a0;           gcur[base + 1] = e + a0; }
    if (base + 2 < nb) { goff[base + 2] = e + a0 + a1;      gcur[base + 2] = e + a0 + a1; }
    if (base + 3 < nb) { goff[base + 3] = e + a0 + a1 + a2; gcur[base + 3] = e + a0 + a1 + a2; }
}

// direct rank-scatter: hist -> per-bucket global reservation -> write at reserved rank.
// packed entry = (dstLocal<<17) | src
__global__ __launch_bounds__(256) void bfill(const int* __restrict__ src, const int* __restrict__ dst,
                                             int* __restrict__ gcur, int* __restrict__ ebuf,
                                             int nE, int nb, int tile)
{
    __shared__ int lh[NBMAX];
    __shared__ int lst[NBMAX];
    const int t = threadIdx.x;
    const int base = blockIdx.x * tile;
    const int nT = min(tile, nE - base);

    for (int i = t; i < nb; i += 256) lh[i] = 0;
    __syncthreads();
    for (int i = t; i < nT; i += 256) atomicAdd(&lh[dst[base + i] >> 7], 1);
    __syncthreads();
    for (int b = t; b < nb; b += 256) {
        int k = lh[b];
        lst[b] = k ? atomicAdd(&gcur[b], k) : 0;
    }
    __syncthreads();
    for (int i = t; i < nT; i += 256) {
        int d = dst[base + i];
        int b = d >> 7;
        int pos = atomicAdd(&lst[b], 1);
        ebuf[pos] = ((d & 127) << 17) | src[base + i];
    }
}

// block per bucket: local counting sort -> esrc (dense), rs/cnt/dis for 128 nodes
__global__ __launch_bounds__(256) void local_csr(const int* __restrict__ ebuf, const int* __restrict__ goff,
                                                 const int* __restrict__ gbh, int* __restrict__ esrc,
                                                 int* __restrict__ rs, int* __restrict__ cnt,
                                                 float* __restrict__ dis, int n, int selfadd)
{
    __shared__ int lcnt[128];
    __shared__ int lrs[128];
    __shared__ int lcur[128];
    const int b = blockIdx.x;
    const int t = threadIdx.x;
    const int off = goff[b];
    const int k = gbh[b];

    if (t < 128) lcnt[t] = 0;
    __syncthreads();
    for (int i = t; i < k; i += 256) atomicAdd(&lcnt[ebuf[off + i] >> 17], 1);
    __syncthreads();
    if (t < 128) lrs[t] = lcnt[t];
    __syncthreads();
    for (int o = 1; o < 128; o <<= 1) {
        int y = (t < 128 && t >= o) ? lrs[t - o] : 0;
        __syncthreads();
        if (t < 128) lrs[t] += y;
        __syncthreads();
    }
    if (t < 128) lcur[t] = lrs[t] - lcnt[t];
    __syncthreads();
    for (int i = t; i < k; i += 256) {
        int v = ebuf[off + i];
        int dL = v >> 17;
        int pos = atomicAdd(&lcur[dL], 1);
        esrc[off + pos] = v & 0x1FFFF;
    }
    int node = b * 128 + t;
    if (t < 128 && node < n) {
        int c = lcnt[t];
        rs[node] = off + (lrs[t] - c);
        cnt[node] = c;
        int dt = c + selfadd;
        dis[node] = dt > 0 ? rsqrtf((float)dt) : 0.0f;
    }
}

// ---- gather: h is pre-scaled by dis[src]; out = lrelu(dd*(sum hs[s] (+hs[d] if SELF)) + bias) ----
template <bool SELF, bool FINAL>
__global__ __launch_bounds__(256) void gather16(const unsigned short* __restrict__ h,
                                                const int* __restrict__ esrc,
                                                const int* __restrict__ rs, const int* __restrict__ cnt,
                                                const float* __restrict__ dis, const float* __restrict__ bias,
                                                unsigned short* __restrict__ out,
                                                const float* __restrict__ Wc, const float* __restrict__ bc,
                                                float* __restrict__ fout, int n)
{
    int d = blockIdx.x * 16 + (threadIdx.x >> 4);
    if (d >= n) return;
    const int l = threadIdx.x & 15;
    const int beg = rs[d];
    const int c = cnt[d];
    const float dd = dis[d];

    float ax0 = 0.f, ay0 = 0.f, az0 = 0.f, aw0 = 0.f;
    float ax1 = 0.f, ay1 = 0.f, az1 = 0.f, aw1 = 0.f;
    int i = 0;
    for (; i + 2 <= c; i += 2) {
        int s0 = esrc[beg + i], s1 = esrc[beg + i + 1];
        ushort4 v0 = *(const ushort4*)(h + (size_t)s0 * H + l * 4);
        ushort4 v1 = *(const ushort4*)(h + (size_t)s1 * H + l * 4);
        ax0 += b2f(v0.x); ay0 += b2f(v0.y); az0 += b2f(v0.z); aw0 += b2f(v0.w);
        ax1 += b2f(v1.x); ay1 += b2f(v1.y); az1 += b2f(v1.z); aw1 += b2f(v1.w);
    }
    if (i < c) {
        int s = esrc[beg + i];
        ushort4 v = *(const ushort4*)(h + (size_t)s * H + l * 4);
        ax0 += b2f(v.x); ay0 += b2f(v.y); az0 += b2f(v.z); aw0 += b2f(v.w);
    }
    if (SELF) {
        ushort4 v = *(const ushort4*)(h + (size_t)d * H + l * 4);
        ax0 += b2f(v.x); ay0 += b2f(v.y); az0 += b2f(v.z); aw0 += b2f(v.w);
    }

    float rx = (ax0 + ax1) * dd, ry = (ay0 + ay1) * dd, rz = (az0 + az1) * dd, rw = (aw0 + aw1) * dd;
    float4 bb = *(const float4*)(bias + l * 4);
    rx = lrelu(rx + bb.x); ry = lrelu(ry + bb.y); rz = lrelu(rz + bb.z); rw = lrelu(rw + bb.w);

    if (FINAL) {
        int f = l * 4;
        float p0 = rx * Wc[(f + 0) * 2] + ry * Wc[(f + 1) * 2] + rz * Wc[(f + 2) * 2] + rw * Wc[(f + 3) * 2];
        float p1 = rx * Wc[(f + 0) * 2 + 1] + ry * Wc[(f + 1) * 2 + 1] + rz * Wc[(f + 2) * 2 + 1] + rw * Wc[(f + 3) * 2 + 1];
        #pragma unroll
        for (int o = 8; o; o >>= 1) {
            p0 += __shfl_xor(p0, o);
            p1 += __shfl_xor(p1, o);
        }
        if (l == 0) {
            float l0 = p0 + bc[0], l1 = p1 + bc[1];
            float m = fmaxf(l0, l1);
            float lse = m + logf(expf(l0 - m) + expf(l1 - m));
            fout[(size_t)d * 2 + 0] = l0 - lse;
            fout[(size_t)d * 2 + 1] = l1 - lse;
        }
    } else {
        ushort4 o;
        o.x = f2b(rx); o.y = f2b(ry); o.z = f2b(rz); o.w = f2b(rw);
        *(ushort4*)(out + (size_t)d * H + l * 4) = o;
    }
}

extern "C" void kernel_launch(void* const* d_in, const int* in_sizes, int n_in,
                              void* d_out, int out_size, void* d_ws, size_t ws_size,
                              hipStream_t stream)
{
    const float* x      = (const float*)d_in[0];
    const int*   ei     = (const int*)d_in[1];
    const float* mx     = (const float*)d_in[2];
    const int*   mei    = (const int*)d_in[3];
    const float* W_lin  = (const float*)d_in[4];
    const float* b_lin  = (const float*)d_in[5];
    const float* W_mlin = (const float*)d_in[6];
    const float* b_mlin = (const float*)d_in[7];
    const float* W0     = (const float*)d_in[8];
    const float* b0     = (const float*)d_in[9];
    const float* W1     = (const float*)d_in[10];
    const float* b1     = (const float*)d_in[11];
    const float* Wm     = (const float*)d_in[12];
    const float* bm     = (const float*)d_in[13];
    const float* Wc     = (const float*)d_in[14];
    const float* bc     = (const float*)d_in[15];

    const int F  = 128;
    const int N  = in_sizes[0] / F;
    const int E  = in_sizes[1] / 2;
    const int M  = in_sizes[2] / F;
    const int Em = in_sizes[3] / 2;
    const int NM = N + M;
    const int* src  = ei;
    const int* dstp = ei + E;
    const int* msrc = mei;
    const int* mdst = mei + Em;
    const int Emax = E > Em ? E : Em;

    unsigned short* hb0 = (unsigned short*)d_ws;        // [NM, H] bf16
    unsigned short* hb1 = hb0 + (size_t)NM * H;         // [NM, H] bf16
    float* disD = (float*)(hb1 + (size_t)NM * H);       // [NM]
    float* disM = disD + NM;                            // [NM]
    int*   cntD = (int*)(disM + NM);                    // [NM]
    int*   rsD  = cntD + NM;                            // [NM]
    int*   cntM = rsD + NM;                             // [NM]
    int*   rsM  = cntM + NM;                            // [NM]
    int*   esrcD = rsM + NM;                            // [E]
    int*   esrcM = esrcD + E;                           // [Em]
    int*   ebuf  = esrcM + Em;                          // [Emax]
    int*   gbh  = ebuf + Emax;                          // [NBMAX]
    int*   goff = gbh + NBMAX;                          // [NBMAX]
    int*   gcur = goff + NBMAX;                         // [NBMAX]

    const int nbD = (N + 127) / 128;
    const int nbM = (NM + 127) / 128;
    const int tileD = 6144;
    const int tileM = 1024;

    // input projections (meta rows go straight to concat slot)
    mfma_gemm<128, true, true, true, false><<<(N + 63) / 64, 256, 0, stream>>>(x, W_lin, b_lin, nullptr, hb0, N);
    mfma_gemm<128, true, true, true, false><<<(M + 63) / 64, 256, 0, stream>>>(mx, W_mlin, b_mlin, nullptr, hb0 + (size_t)N * H, M);

    // data-graph CSR (reused by both GCN layers)
    zero_i<<<(NBMAX + 255) / 256, 256, 0, stream>>>(gbh, NBMAX);
    bhist<<<min(256, (E + 255) / 256), 256, 0, stream>>>(dstp, gbh, E, nbD);
    bscan<<<1, 256, 0, stream>>>(gbh, goff, gcur, nbD);
    bfill<<<(E + tileD - 1) / tileD, 256, 0, stream>>>(src, dstp, gcur, ebuf, E, nbD, tileD);
    local_csr<<<nbD, 256, 0, stream>>>(ebuf, goff, gbh, esrcD, rsD, cntD, disD, N, 1);

    // meta-graph CSR
    zero_i<<<(NBMAX + 255) / 256, 256, 0, stream>>>(gbh, NBMAX);
    bhist<<<min(256, (Em + 255) / 256), 256, 0, stream>>>(mdst, gbh, Em, nbM);
    bscan<<<1, 256, 0, stream>>>(gbh, goff, gcur, nbM);
    bfill<<<(Em + tileM - 1) / tileM, 256, 0, stream>>>(msrc, mdst, gcur, ebuf, Em, nbM, tileM);
    local_csr<<<nbM, 256, 0, stream>>>(ebuf, goff, gbh, esrcM, rsM, cntM, disM, NM, 0);

    // GCN layer 0 (GEMM output pre-scaled by disD)
    mfma_gemm<64, false, false, false, true><<<(N + 63) / 64, 256, 0, stream>>>(hb0, W0, nullptr, disD, hb1, N);
    gather16<true, false><<<(N + 15) / 16, 256, 0, stream>>>(hb1, esrcD, rsD, cntD, disD, b0, hb0, nullptr, nullptr, nullptr, N);

    // GCN layer 1
    mfma_gemm<64, false, false, false, true><<<(N + 63) / 64, 256, 0, stream>>>(hb0, W1, nullptr, disD, hb1, N);
    gather16<true, false><<<(N + 15) / 16, 256, 0, stream>>>(hb1, esrcD, rsD, cntD, disD, b1, hb0, nullptr, nullptr, nullptr, N);

    // meta fusion GEMM over z = hb0[0..NM), pre-scaled by disM
    mfma_gemm<64, false, false, false, true><<<(NM + 63) / 64, 256, 0, stream>>>(hb0, Wm, nullptr, disM, hb1, NM);

    // final gather + fused classifier + log_softmax
    gather16<false, true><<<(NM + 15) / 16, 256, 0, stream>>>(hb1, esrcM, rsM, cntM, disM, bm, nullptr, Wc, bc, (float*)d_out, NM);
}

// Round 6
// 288.032 us; speedup vs baseline: 4.2876x; 1.0143x over previous
//
#include <hip/hip_runtime.h>
#include <cstddef>

static constexpr float ALPHA = 0.2f;
static constexpr int H = 64;
static constexpr int NBMAX = 2048;   // combined buckets (128 nodes each)
static constexpr int BTILE = 2048;   // bfill edges per block (8/thread)

typedef __attribute__((ext_vector_type(8))) short short8;
typedef __attribute__((ext_vector_type(4))) float floatx4;

__device__ __forceinline__ float lrelu(float v) { return v >= 0.0f ? v : ALPHA * v; }

__device__ __forceinline__ float b2f(unsigned short u)
{
    union { unsigned int i; float f; } x;
    x.i = ((unsigned int)u) << 16;
    return x.f;
}

__device__ __forceinline__ unsigned short f2b(float f)
{
    union { float f; unsigned int i; } x;
    x.f = f;
    unsigned int r = x.i + 0x7fffu + ((x.i >> 16) & 1u);  // RNE
    return (unsigned short)(r >> 16);
}

// ---- MFMA GEMM: out[rows,64](bf16) = act(in[rows,K] @ W[K,64] (+bias)) (* scl[row]) ----
template <int K, bool AF32, bool BIAS, bool ACT, bool SCALE>
__global__ __launch_bounds__(256) void mfma_gemm(
    const void* __restrict__ in_v, const float* __restrict__ W,
    const float* __restrict__ bias, const float* __restrict__ scl,
    unsigned short* __restrict__ out, int rows)
{
    constexpr int S = K / 32;
    __shared__ short8 WL[4 * S * 64];

    for (int f = threadIdx.x; f < 4 * S * 64; f += 256) {
        int c = f / (S * 64);
        int rem = f % (S * 64);
        int s = rem / 64;
        int l = rem % 64;
        short8 frag;
        #pragma unroll
        for (int j = 0; j < 8; ++j) {
            int k = s * 32 + (l >> 4) * 8 + j;
            int col = c * 16 + (l & 15);
            frag[j] = (short)f2b(W[k * H + col]);
        }
        WL[f] = frag;
    }
    __syncthreads();

    const int l = threadIdx.x & 63;
    const int wv = threadIdx.x >> 6;
    const int rowBase = blockIdx.x * 64 + wv * 16;
    if (rowBase >= rows) return;
    const int arow = min(rowBase + (l & 15), rows - 1);

    floatx4 acc0 = {0.f, 0.f, 0.f, 0.f};
    floatx4 acc1 = {0.f, 0.f, 0.f, 0.f};
    floatx4 acc2 = {0.f, 0.f, 0.f, 0.f};
    floatx4 acc3 = {0.f, 0.f, 0.f, 0.f};

    #pragma unroll
    for (int s = 0; s < S; ++s) {
        short8 a;
        if (AF32) {
            const float* ap = (const float*)in_v + (size_t)arow * K + s * 32 + (l >> 4) * 8;
            float4 f0 = *(const float4*)(ap + 0);
            float4 f1 = *(const float4*)(ap + 4);
            a[0] = (short)f2b(f0.x); a[1] = (short)f2b(f0.y);
            a[2] = (short)f2b(f0.z); a[3] = (short)f2b(f0.w);
            a[4] = (short)f2b(f1.x); a[5] = (short)f2b(f1.y);
            a[6] = (short)f2b(f1.z); a[7] = (short)f2b(f1.w);
        } else {
            a = *(const short8*)((const unsigned short*)in_v + (size_t)arow * K + s * 32 + (l >> 4) * 8);
        }
        acc0 = __builtin_amdgcn_mfma_f32_16x16x32_bf16(a, WL[(0 * S + s) * 64 + l], acc0, 0, 0, 0);
        acc1 = __builtin_amdgcn_mfma_f32_16x16x32_bf16(a, WL[(1 * S + s) * 64 + l], acc1, 0, 0, 0);
        acc2 = __builtin_amdgcn_mfma_f32_16x16x32_bf16(a, WL[(2 * S + s) * 64 + l], acc2, 0, 0, 0);
        acc3 = __builtin_amdgcn_mfma_f32_16x16x32_bf16(a, WL[(3 * S + s) * 64 + l], acc3, 0, 0, 0);
    }

    #pragma unroll
    for (int j = 0; j < 4; ++j) {
        int row = rowBase + (l >> 4) * 4 + j;
        if (row >= rows) continue;
        unsigned short* orow = out + (size_t)row * H;
        float sc = SCALE ? scl[row] : 1.0f;
        float v;
        int col = l & 15;
        v = acc0[j] + (BIAS ? bias[col] : 0.f);      if (ACT) v = lrelu(v); orow[col]      = f2b(v * sc);
        v = acc1[j] + (BIAS ? bias[col + 16] : 0.f); if (ACT) v = lrelu(v); orow[col + 16] = f2b(v * sc);
        v = acc2[j] + (BIAS ? bias[col + 32] : 0.f); if (ACT) v = lrelu(v); orow[col + 32] = f2b(v * sc);
        v = acc3[j] + (BIAS ? bias[col + 48] : 0.f); if (ACT) v = lrelu(v); orow[col + 48] = f2b(v * sc);
    }
}

// ---------------- combined bucket-sort CSR build (data graph + meta graph in one pass) ----------------
// virtual bucket space: [0, nbD) data buckets (dst>>7), [nbD, nbD+nbM) meta buckets.
// packed entry = (dstLocal<<17) | src   (src < 2^17, dstLocal < 128)

__global__ __launch_bounds__(256) void zero_i(int* __restrict__ p, int n)
{
    int i = blockIdx.x * 256 + threadIdx.x;
    if (i < n) p[i] = 0;
}

__global__ __launch_bounds__(256) void bhist(const int* __restrict__ dstD, const int* __restrict__ dstM,
                                             int* __restrict__ gbh, int E, int Et, int nbD, int nbT)
{
    __shared__ int lh[NBMAX];
    for (int i = threadIdx.x; i < nbT; i += 256) lh[i] = 0;
    __syncthreads();
    for (int j = blockIdx.x * 256 + threadIdx.x; j < Et; j += 256 * gridDim.x) {
        int b = (j < E) ? (dstD[j] >> 7) : (nbD + (dstM[j - E] >> 7));
        atomicAdd(&lh[b], 1);
    }
    __syncthreads();
    for (int b = threadIdx.x; b < nbT; b += 256) {
        int v = lh[b];
        if (v) atomicAdd(&gbh[b], v);
    }
}

// single-block exclusive scan (nb <= 2048, 8 per thread)
__global__ __launch_bounds__(256) void bscan(const int* __restrict__ gbh, int* __restrict__ goff,
                                             int* __restrict__ gcur, int nb)
{
    __shared__ int sp[256];
    int t = threadIdx.x;
    int base = t * 8;
    int a[8];
    int s = 0;
    #pragma unroll
    for (int u = 0; u < 8; ++u) {
        a[u] = (base + u < nb) ? gbh[base + u] : 0;
        s += a[u];
    }
    sp[t] = s;
    __syncthreads();
    for (int o = 1; o < 256; o <<= 1) {
        int y = (t >= o) ? sp[t - o] : 0;
        __syncthreads();
        sp[t] += y;
        __syncthreads();
    }
    int e = sp[t] - s;
    #pragma unroll
    for (int u = 0; u < 8; ++u) {
        if (base + u < nb) { goff[base + u] = e; gcur[base + u] = e; }
        e += a[u];
    }
}

// direct rank-scatter over the combined edge list; edges cached in registers between passes
__global__ __launch_bounds__(256) void bfill(const int* __restrict__ srcD, const int* __restrict__ dstD,
                                             const int* __restrict__ srcM, const int* __restrict__ dstM,
                                             int* __restrict__ gcur, int* __restrict__ ebuf,
                                             int E, int Et, int nbD, int nbT)
{
    __shared__ int lh[NBMAX];
    __shared__ int lst[NBMAX];
    const int t = threadIdx.x;
    const int base = blockIdx.x * BTILE;

    for (int i = t; i < nbT; i += 256) lh[i] = 0;
    __syncthreads();

    int bb[8], pk[8];
    #pragma unroll
    for (int u = 0; u < 8; ++u) {
        int j = base + u * 256 + t;
        if (j < Et) {
            int d, sv;
            if (j < E) { d = dstD[j]; sv = srcD[j]; bb[u] = d >> 7; }
            else       { d = dstM[j - E]; sv = srcM[j - E]; bb[u] = nbD + (d >> 7); }
            pk[u] = ((d & 127) << 17) | sv;
            atomicAdd(&lh[bb[u]], 1);
        } else bb[u] = -1;
    }
    __syncthreads();

    for (int b = t; b < nbT; b += 256) {
        int k = lh[b];
        lst[b] = k ? atomicAdd(&gcur[b], k) : 0;
    }
    __syncthreads();

    #pragma unroll
    for (int u = 0; u < 8; ++u) {
        if (bb[u] >= 0) {
            int pos = atomicAdd(&lst[bb[u]], 1);
            ebuf[pos] = pk[u];
        }
    }
}

// block per bucket: local counting sort -> esrc (dense) + rs/cnt/dis in virtual node space
__global__ __launch_bounds__(256) void local_csr(const int* __restrict__ ebuf, const int* __restrict__ goff,
                                                 const int* __restrict__ gbh, int* __restrict__ esrc,
                                                 int* __restrict__ rs, int* __restrict__ cnt,
                                                 float* __restrict__ dis, int nbD, int N, int NM)
{
    __shared__ int lcnt[128];
    __shared__ int lrs[128];
    __shared__ int lcur[128];
    const int b = blockIdx.x;
    const int t = threadIdx.x;
    const int off = goff[b];
    const int k = gbh[b];
    const bool isData = b < nbD;

    if (t < 128) lcnt[t] = 0;
    __syncthreads();
    for (int i = t; i < k; i += 256) atomicAdd(&lcnt[ebuf[off + i] >> 17], 1);
    __syncthreads();
    if (t < 128) lrs[t] = lcnt[t];
    __syncthreads();
    for (int o = 1; o < 128; o <<= 1) {
        int y = (t < 128 && t >= o) ? lrs[t - o] : 0;
        __syncthreads();
        if (t < 128) lrs[t] += y;
        __syncthreads();
    }
    if (t < 128) lcur[t] = lrs[t] - lcnt[t];
    __syncthreads();
    for (int i = t; i < k; i += 256) {
        int v = ebuf[off + i];
        int dL = v >> 17;
        int pos = atomicAdd(&lcur[dL], 1);
        esrc[off + pos] = v & 0x1FFFF;
    }
    if (t < 128) {
        int local = isData ? b * 128 + t : (b - nbD) * 128 + t;
        int lim = isData ? N : NM;
        if (local < lim) {
            int slot = isData ? local : N + local;
            int c = lcnt[t];
            rs[slot] = off + (lrs[t] - c);
            cnt[slot] = c;
            int dt = c + (isData ? 1 : 0);
            dis[slot] = dt > 0 ? rsqrtf((float)dt) : 0.0f;
        }
    }
}

// ---- wave-per-dst gather: lanes = 4 edge slots x 16 feature quads; h pre-scaled by dis[src] ----
template <bool SELF, bool FINAL>
__global__ __launch_bounds__(256) void gather_w(const unsigned short* __restrict__ h,
                                                const int* __restrict__ esrc,
                                                const int* __restrict__ rs, const int* __restrict__ cnt,
                                                const float* __restrict__ dis, const float* __restrict__ bias,
                                                unsigned short* __restrict__ out,
                                                const float* __restrict__ Wc, const float* __restrict__ bc,
                                                float* __restrict__ fout, int n)
{
    int d = blockIdx.x * 4 + (threadIdx.x >> 6);
    if (d >= n) return;
    const int l = threadIdx.x & 63;
    const int g = l >> 4;      // edge slot 0..3
    const int fq = l & 15;     // feature quad
    const int beg = rs[d];
    const int c = cnt[d];
    const float dd = dis[d];

    float ax0 = 0.f, ay0 = 0.f, az0 = 0.f, aw0 = 0.f;
    float ax1 = 0.f, ay1 = 0.f, az1 = 0.f, aw1 = 0.f;
    int i = g;
    for (; i + 4 < c; i += 8) {
        int s0 = esrc[beg + i], s1 = esrc[beg + i + 4];
        ushort4 v0 = *(const ushort4*)(h + (size_t)s0 * H + fq * 4);
        ushort4 v1 = *(const ushort4*)(h + (size_t)s1 * H + fq * 4);
        ax0 += b2f(v0.x); ay0 += b2f(v0.y); az0 += b2f(v0.z); aw0 += b2f(v0.w);
        ax1 += b2f(v1.x); ay1 += b2f(v1.y); az1 += b2f(v1.z); aw1 += b2f(v1.w);
    }
    if (i < c) {
        int s = esrc[beg + i];
        ushort4 v = *(const ushort4*)(h + (size_t)s * H + fq * 4);
        ax0 += b2f(v.x); ay0 += b2f(v.y); az0 += b2f(v.z); aw0 += b2f(v.w);
    }

    float rx = ax0 + ax1, ry = ay0 + ay1, rz = az0 + az1, rw = aw0 + aw1;
    rx += __shfl_xor(rx, 16); rx += __shfl_xor(rx, 32);
    ry += __shfl_xor(ry, 16); ry += __shfl_xor(ry, 32);
    rz += __shfl_xor(rz, 16); rz += __shfl_xor(rz, 32);
    rw += __shfl_xor(rw, 16); rw += __shfl_xor(rw, 32);

    if (SELF) {
        ushort4 v = *(const ushort4*)(h + (size_t)d * H + fq * 4);
        rx += b2f(v.x); ry += b2f(v.y); rz += b2f(v.z); rw += b2f(v.w);
    }
    float4 bb = *(const float4*)(bias + fq * 4);
    rx = lrelu(rx * dd + bb.x); ry = lrelu(ry * dd + bb.y);
    rz = lrelu(rz * dd + bb.z); rw = lrelu(rw * dd + bb.w);

    if (FINAL) {
        int f = fq * 4;
        float p0 = rx * Wc[(f + 0) * 2] + ry * Wc[(f + 1) * 2] + rz * Wc[(f + 2) * 2] + rw * Wc[(f + 3) * 2];
        float p1 = rx * Wc[(f + 0) * 2 + 1] + ry * Wc[(f + 1) * 2 + 1] + rz * Wc[(f + 2) * 2 + 1] + rw * Wc[(f + 3) * 2 + 1];
        #pragma unroll
        for (int o = 8; o; o >>= 1) {
            p0 += __shfl_xor(p0, o);
            p1 += __shfl_xor(p1, o);
        }
        if (l == 0) {
            float l0 = p0 + bc[0], l1 = p1 + bc[1];
            float m = fmaxf(l0, l1);
            float lse = m + logf(expf(l0 - m) + expf(l1 - m));
            fout[(size_t)d * 2 + 0] = l0 - lse;
            fout[(size_t)d * 2 + 1] = l1 - lse;
        }
    } else {
        if (g == 0) {
            ushort4 o;
            o.x = f2b(rx); o.y = f2b(ry); o.z = f2b(rz); o.w = f2b(rw);
            *(ushort4*)(out + (size_t)d * H + fq * 4) = o;
        }
    }
}

extern "C" void kernel_launch(void* const* d_in, const int* in_sizes, int n_in,
                              void* d_out, int out_size, void* d_ws, size_t ws_size,
                              hipStream_t stream)
{
    const float* x      = (const float*)d_in[0];
    const int*   ei     = (const int*)d_in[1];
    const float* mx     = (const float*)d_in[2];
    const int*   mei    = (const int*)d_in[3];
    const float* W_lin  = (const float*)d_in[4];
    const float* b_lin  = (const float*)d_in[5];
    const float* W_mlin = (const float*)d_in[6];
    const float* b_mlin = (const float*)d_in[7];
    const float* W0     = (const float*)d_in[8];
    const float* b0     = (const float*)d_in[9];
    const float* W1     = (const float*)d_in[10];
    const float* b1     = (const float*)d_in[11];
    const float* Wm     = (const float*)d_in[12];
    const float* bm     = (const float*)d_in[13];
    const float* Wc     = (const float*)d_in[14];
    const float* bc     = (const float*)d_in[15];

    const int F  = 128;
    const int N  = in_sizes[0] / F;
    const int E  = in_sizes[1] / 2;
    const int M  = in_sizes[2] / F;
    const int Em = in_sizes[3] / 2;
    const int NM = N + M;
    const int Et = E + Em;
    const int* src  = ei;
    const int* dstp = ei + E;
    const int* msrc = mei;
    const int* mdst = mei + Em;

    unsigned short* hb0 = (unsigned short*)d_ws;        // [NM, H] bf16
    unsigned short* hb1 = hb0 + (size_t)NM * H;         // [NM, H] bf16
    float* disV = (float*)(hb1 + (size_t)NM * H);       // [N + NM]
    int*   cntV = (int*)(disV + (N + NM));              // [N + NM]
    int*   rsV  = cntV + (N + NM);                      // [N + NM]
    int*   esrcA = rsV + (N + NM);                      // [Et]
    int*   ebuf  = esrcA + Et;                          // [Et]
    int*   gbh  = ebuf + Et;                            // [NBMAX]
    int*   goff = gbh + NBMAX;                          // [NBMAX]
    int*   gcur = goff + NBMAX;                         // [NBMAX]

    const int nbD = (N + 127) / 128;
    const int nbM = (NM + 127) / 128;
    const int nbT = nbD + nbM;

    // input projections (meta rows go straight to concat slot)
    mfma_gemm<128, true, true, true, false><<<(N + 63) / 64, 256, 0, stream>>>(x, W_lin, b_lin, nullptr, hb0, N);
    mfma_gemm<128, true, true, true, false><<<(M + 63) / 64, 256, 0, stream>>>(mx, W_mlin, b_mlin, nullptr, hb0 + (size_t)N * H, M);

    // combined CSR build (data + meta graphs in one pass)
    zero_i<<<(NBMAX + 255) / 256, 256, 0, stream>>>(gbh, NBMAX);
    bhist<<<256, 256, 0, stream>>>(dstp, mdst, gbh, E, Et, nbD, nbT);
    bscan<<<1, 256, 0, stream>>>(gbh, goff, gcur, nbT);
    bfill<<<(Et + BTILE - 1) / BTILE, 256, 0, stream>>>(src, dstp, msrc, mdst, gcur, ebuf, E, Et, nbD, nbT);
    local_csr<<<nbT, 256, 0, stream>>>(ebuf, goff, gbh, esrcA, rsV, cntV, disV, nbD, N, NM);

    // GCN layer 0 (GEMM output pre-scaled by dis)
    mfma_gemm<64, false, false, false, true><<<(N + 63) / 64, 256, 0, stream>>>(hb0, W0, nullptr, disV, hb1, N);
    gather_w<true, false><<<(N + 3) / 4, 256, 0, stream>>>(hb1, esrcA, rsV, cntV, disV, b0, hb0, nullptr, nullptr, nullptr, N);

    // GCN layer 1
    mfma_gemm<64, false, false, false, true><<<(N + 63) / 64, 256, 0, stream>>>(hb0, W1, nullptr, disV, hb1, N);
    gather_w<true, false><<<(N + 3) / 4, 256, 0, stream>>>(hb1, esrcA, rsV, cntV, disV, b1, hb0, nullptr, nullptr, nullptr, N);

    // meta fusion GEMM over z = hb0[0..NM), pre-scaled by meta dis
    mfma_gemm<64, false, false, false, true><<<(NM + 63) / 64, 256, 0, stream>>>(hb0, Wm, nullptr, disV + N, hb1, NM);

    // final gather + fused classifier + log_softmax (meta CSR lives at virtual offset N)
    gather_w<false, true><<<(NM + 3) / 4, 256, 0, stream>>>(hb1, esrcA, rsV + N, cntV + N, disV + N, bm, nullptr, Wc, bc, (float*)d_out, NM);
}